// Round 2
// baseline (3780.339 us; speedup 1.0000x reference)
//
#include <hip/hip_runtime.h>
#include <hip/hip_bf16.h>

// ---------------------------------------------------------------------------
// VisionMamba, round 13: persistent mega-kernel — all 24 layers in ONE
// dispatch with device-scope grid barriers between stages.
// B=8, L=196, D_MODEL=192, D_INNER=384, D_STATE=16, DT_RANK=12, DEPTH=24.
//
// R12 evidence: wall 1421us, every one of our dispatches < 42us; ~57us/layer
// vs ~28us stage work -> ~700us of launch/ramp gaps across 96 dependent
// dispatches. Fix: fuse the per-layer pipeline (gemm_in -> conv_xproj_dt ->
// scan -> gemm_ln) into one persistent kernel, 512 blocks (2/CU by
// construction: LDS union 69KB <= 80KB, launch_bounds(256,2)), hand-rolled
// two-level epoch barrier (64 groups -> root -> epoch) with AGENT-scope
// atomics for cross-XCD coherence. Stage bodies transcribed verbatim from
// the R12-verified kernels. prep zeroes barrier state each launch.
// ---------------------------------------------------------------------------

#define NTOK   1568   // B * L
#define DMODEL 192
#define DINNER 384
#define DSTATE 16
#define DTRANK 12
#define DEPTH  24
#define LSEQ   196
#define TCH    49     // scan time-chunk (196 = 4*49)
#define LDA    40     // LDS row stride in bf16 elements (80B)
#define SPAD   272
#define NB     512    // persistent grid: 2 blocks/CU on 256 CUs

typedef __attribute__((ext_vector_type(8))) short short8;
typedef __attribute__((ext_vector_type(4))) short short4v;
typedef __attribute__((ext_vector_type(4))) float floatx4;

__device__ inline short f2bf(float f) {
    __hip_bfloat16 h = __float2bfloat16(f);
    return *reinterpret_cast<short*>(&h);
}

// ---------------- LDS union for the mega-kernel stages ----------------
struct GiLDS { short As[64 * LDA]; short Ws[64 * LDA]; };                    // 10,240 B
struct CvLDS { float sxz[7 * 384]; float su[4 * 384]; float sx[4 * 48]; };   // 17,664 B
struct ScLDS {
    float sdt[TCH][16]; float su_[TCH][16]; float sz_[TCH][16];
    float sB_[TCH][16]; float sC_[TCH][16]; float sprod[TCH][SPAD];          // 68,992 B
};
struct GlLDS {
    short As[16 * LDA]; short Ws[192 * LDA];
    float slw[192]; float slb[192]; float sS1[4][16]; float sS2[4][16];      // 17,920 B
};
union MegaLDS { GiLDS gi; CvLDS cv; ScLDS sc; GlLDS gl; };

// ---------------- two-level grid barrier (epoch-based, monotone) ----------------
// bar[0]=epoch, bar[16]=root counter, bar[32+g*16]=group g counter (g<64).
// 512 blocks = 64 groups of 8. Counters monotone; zeroed by prep each launch.
__device__ __forceinline__ void gridbar(unsigned* bar, unsigned eph) {
    __syncthreads();   // drains this block's vmem (s_waitcnt vmcnt(0) before s_barrier)
    if (threadIdx.x == 0) {
        unsigned g = (unsigned)blockIdx.x >> 3;
        unsigned prev = __hip_atomic_fetch_add(&bar[32 + g * 16], 1u,
                          __ATOMIC_ACQ_REL, __HIP_MEMORY_SCOPE_AGENT);
        if (prev == (eph << 3) + 7u) {              // last of my 8-block group
            unsigned rprev = __hip_atomic_fetch_add(&bar[16], 1u,
                              __ATOMIC_ACQ_REL, __HIP_MEMORY_SCOPE_AGENT);
            if (rprev == eph * (NB >> 3) + (NB >> 3) - 1u) {   // last group
                __hip_atomic_store(&bar[0], eph + 1u,
                    __ATOMIC_RELEASE, __HIP_MEMORY_SCOPE_AGENT);
            }
        }
        unsigned tmo = 0;
        while (__hip_atomic_load(&bar[0], __ATOMIC_RELAXED,
                                 __HIP_MEMORY_SCOPE_AGENT) <= eph) {
            __builtin_amdgcn_s_sleep(4);
            if (++tmo > 100000u) break;   // failsafe: wrong answer, not a hang
        }
        // one acquire to establish ordering (single buffer_inv, not per-poll)
        (void)__hip_atomic_load(&bar[0], __ATOMIC_ACQUIRE, __HIP_MEMORY_SCOPE_AGENT);
    }
    __syncthreads();
}

// ---------------- merged pre-stage: weight cvt + transposes + im2col + bar zero --------
#define PR1 884736
#define PR2 1327104   // +442368
#define PR3 1363968   // +36864
#define PR4 1769472   // +405504
#define PR5 1880064   // +110592
#define PR6 3084288   // +1204224
#define PR7 3086336   // +2048 (barrier state zero)
__global__ __launch_bounds__(256) void prep(
    const float* __restrict__ inw, const float* __restrict__ outw,
    const float* __restrict__ pew, const float* __restrict__ xpw,
    const float* __restrict__ dtw, const float* __restrict__ x,
    short* __restrict__ w_in, short* __restrict__ w_out,
    short* __restrict__ w_pe, float* __restrict__ xpwT,
    float* __restrict__ dtwT, __hip_bfloat16* __restrict__ patches,
    unsigned* __restrict__ bar)
{
    int idx = blockIdx.x * 256 + threadIdx.x;
    if (idx < PR3) {
        float4 v; short* dst;
        if (idx < PR1)      { v = ((const float4*)inw)[idx];        dst = w_in  + (size_t)idx * 4; }
        else if (idx < PR2) { int i = idx - PR1; v = ((const float4*)outw)[i]; dst = w_out + (size_t)i * 4; }
        else                { int i = idx - PR2; v = ((const float4*)pew)[i];  dst = w_pe  + (size_t)i * 4; }
        short4v o;
        o[0] = f2bf(v.x); o[1] = f2bf(v.y); o[2] = f2bf(v.z); o[3] = f2bf(v.w);
        *(short4v*)dst = o;
    } else if (idx < PR4) {
        int i = idx - PR3;                    // xpwT[layer][k][e] = xpw[layer][e][k]
        int layer = i / 16896, rem = i % 16896;
        int k = rem / 44, e = rem % 44;
        xpwT[i] = xpw[(size_t)layer * 16896 + e * 384 + k];
    } else if (idx < PR5) {
        int i = idx - PR4;                    // dtwT[layer][r][d] = dtw[layer][d][r]
        int layer = i / 4608, rem = i % 4608;
        int r = rem / 384, d = rem % 384;
        dtwT[i] = dtw[(size_t)layer * 4608 + d * 12 + r];
    } else if (idx < PR6) {
        int i = idx - PR5;                    // im2col
        int tok = i / 768, e = i % 768;
        int b = tok / LSEQ, l = tok % LSEQ;
        int py = l / 14, px = l % 14;
        int ic = e >> 8, rem = e & 255, ky = rem >> 4, kx = rem & 15;
        patches[i] = __float2bfloat16(x[((b * 3 + ic) * 224 + py * 16 + ky) * 224 + px * 16 + kx]);
    } else if (idx < PR7) {
        bar[idx - PR6] = 0u;
    }
}

// ---------------- standalone gemm_ln (used once for patch-embed + LN0) ----------------
template<int K>
__global__ __launch_bounds__(256) void gemm_ln(
    const __hip_bfloat16* __restrict__ A, const short* __restrict__ Wb,
    const float* __restrict__ bias, float* __restrict__ residual,
    __hip_bfloat16* __restrict__ hn, float* __restrict__ outf,
    const float* __restrict__ lnw, const float* __restrict__ lnb,
    int accumulate)
{
    __shared__ short As[16 * LDA];
    __shared__ short Ws[192 * LDA];
    __shared__ float slw[192], slb[192], sbias[192];
    __shared__ float sS1[4][16], sS2[4][16];
    int tid = threadIdx.x;
    int m0 = blockIdx.x * 16;
    int wv = tid >> 6, lane = tid & 63;
    int fm = lane & 15, q = lane >> 4;
    int wrow = tid >> 2, kc = (tid & 3) * 8;
    if (tid < 192) {
        slw[tid] = lnw[tid];
        slb[tid] = lnb[tid];
        sbias[tid] = bias ? bias[tid] : 0.f;
    }
    const short* Ab = (const short*)A;
    floatx4 acc[3];
#pragma unroll
    for (int j = 0; j < 3; ++j) acc[j] = (floatx4){0.f, 0.f, 0.f, 0.f};

    short8 aR = {0,0,0,0,0,0,0,0};
    short8 wR[3];
    if (tid < 64) aR = *(const short8*)&Ab[(size_t)(m0 + (tid >> 2)) * K + kc];
#pragma unroll
    for (int j = 0; j < 3; ++j)
        wR[j] = *(const short8*)&Wb[(size_t)(wrow + 64 * j) * K + kc];

    for (int k0 = 0; k0 < K; k0 += 32) {
        if (tid < 64) *(short8*)&As[(tid >> 2) * LDA + kc] = aR;
#pragma unroll
        for (int j = 0; j < 3; ++j)
            *(short8*)&Ws[(wrow + 64 * j) * LDA + kc] = wR[j];
        __syncthreads();
        int kn = k0 + 32;
        if (kn < K) {
            if (tid < 64) aR = *(const short8*)&Ab[(size_t)(m0 + (tid >> 2)) * K + kn + kc];
#pragma unroll
            for (int j = 0; j < 3; ++j)
                wR[j] = *(const short8*)&Wb[(size_t)(wrow + 64 * j) * K + kn + kc];
        }
        short8 af = *(const short8*)&As[fm * LDA + q * 8];
#pragma unroll
        for (int j = 0; j < 3; ++j) {
            int ct = wv * 3 + j;
            short8 bf = *(const short8*)&Ws[(ct * 16 + fm) * LDA + q * 8];
            acc[j] = __builtin_amdgcn_mfma_f32_16x16x32_bf16(af, bf, acc[j], 0, 0, 0);
        }
        __syncthreads();
    }

    float v[3][4];
#pragma unroll
    for (int r = 0; r < 4; ++r) {
        int m = m0 + q * 4 + r;
#pragma unroll
        for (int j = 0; j < 3; ++j) {
            int col = (wv * 3 + j) * 16 + fm;
            float t = acc[j][r] + sbias[col];
            if (accumulate) t += residual[(size_t)m * DMODEL + col];
            v[j][r] = t;
        }
    }
#pragma unroll
    for (int r = 0; r < 4; ++r) {
        int m = m0 + q * 4 + r;
#pragma unroll
        for (int j = 0; j < 3; ++j)
            residual[(size_t)m * DMODEL + (wv * 3 + j) * 16 + fm] = v[j][r];
    }
#pragma unroll
    for (int r = 0; r < 4; ++r) {
        float s1 = v[0][r] + v[1][r] + v[2][r];
        float s2 = v[0][r]*v[0][r] + v[1][r]*v[1][r] + v[2][r]*v[2][r];
        s1 += __shfl_xor(s1, 1); s2 += __shfl_xor(s2, 1);
        s1 += __shfl_xor(s1, 2); s2 += __shfl_xor(s2, 2);
        s1 += __shfl_xor(s1, 4); s2 += __shfl_xor(s2, 4);
        s1 += __shfl_xor(s1, 8); s2 += __shfl_xor(s2, 8);
        if (fm == 0) { sS1[wv][q * 4 + r] = s1; sS2[wv][q * 4 + r] = s2; }
    }
    __syncthreads();
#pragma unroll
    for (int r = 0; r < 4; ++r) {
        int row = q * 4 + r;
        int m = m0 + row;
        float S1 = sS1[0][row] + sS1[1][row] + sS1[2][row] + sS1[3][row];
        float S2 = sS2[0][row] + sS2[1][row] + sS2[2][row] + sS2[3][row];
        float mean = S1 * (1.f / DMODEL);
        float var  = S2 * (1.f / DMODEL) - mean * mean;
        float rstd = rsqrtf(var + 1e-5f);
#pragma unroll
        for (int j = 0; j < 3; ++j) {
            int col = (wv * 3 + j) * 16 + fm;
            float o = (v[j][r] - mean) * rstd * slw[col] + slb[col];
            if (outf) outf[(size_t)m * DMODEL + col] = o;
            else      hn[(size_t)m * DMODEL + col] = __float2bfloat16(o);
        }
    }
}

// ---------------- the persistent mega-kernel: all 24 layers ----------------
__global__ __launch_bounds__(256, 2) void vim_mega(
    const short* __restrict__ w_in, const float* __restrict__ conv_w,
    const float* __restrict__ conv_b, const float* __restrict__ xpwT,
    const float* __restrict__ dtwT, const float* __restrict__ dtb_all,
    const float* __restrict__ A_log, const float* __restrict__ D_param,
    const short* __restrict__ w_out, const float* __restrict__ norm_w,
    const float* __restrict__ norm_b, const float* __restrict__ normf_w,
    const float* __restrict__ normf_b, float* __restrict__ residual,
    float* __restrict__ xz, float* __restrict__ ubuf,
    float* __restrict__ dtbuf, float* __restrict__ bcbuf,
    __hip_bfloat16* __restrict__ hn, __hip_bfloat16* __restrict__ ybf,
    float* __restrict__ outF, unsigned* __restrict__ bar)
{
    __shared__ MegaLDS sm;
    int tid = threadIdx.x;
    unsigned eph = 0;

    for (int L = 0; L < DEPTH; ++L) {
        // ======== stage 1: xz[1568,768] = hn[1568,192] @ w_in^T (300 tiles) ========
        if (blockIdx.x < 300) {
            const short* wi = w_in + (size_t)L * 768 * DMODEL;
            int m0 = (blockIdx.x / 12) * 64, n0 = (blockIdx.x % 12) * 64;
            int wv = tid >> 6, lane = tid & 63;
            int fm = lane & 15, q = lane >> 4;
            int row = tid >> 2, kc = (tid & 3) * 8;
            const short* Ab = (const short*)hn;
            floatx4 acc[4];
#pragma unroll
            for (int nt = 0; nt < 4; ++nt) acc[nt] = (floatx4){0.f, 0.f, 0.f, 0.f};
#pragma unroll
            for (int k0 = 0; k0 < DMODEL; k0 += 32) {
                {
                    int m = m0 + row;
                    short8 v = {0,0,0,0,0,0,0,0};
                    if (m < NTOK) v = *(const short8*)&Ab[(size_t)m * DMODEL + k0 + kc];
                    *(short8*)&sm.gi.As[row * LDA + kc] = v;
                }
                {
                    short8 w = *(const short8*)&wi[(size_t)(n0 + row) * DMODEL + k0 + kc];
                    *(short8*)&sm.gi.Ws[row * LDA + kc] = w;
                }
                __syncthreads();
                short8 af = *(const short8*)&sm.gi.As[(wv * 16 + fm) * LDA + q * 8];
#pragma unroll
                for (int nt = 0; nt < 4; ++nt) {
                    short8 bf = *(const short8*)&sm.gi.Ws[(nt * 16 + fm) * LDA + q * 8];
                    acc[nt] = __builtin_amdgcn_mfma_f32_16x16x32_bf16(af, bf, acc[nt], 0, 0, 0);
                }
                __syncthreads();
            }
#pragma unroll
            for (int nt = 0; nt < 4; ++nt) {
                int col = n0 + nt * 16 + fm;
#pragma unroll
                for (int r = 0; r < 4; ++r) {
                    int mrow = m0 + wv * 16 + q * 4 + r;
                    if (mrow < NTOK) xz[(size_t)mrow * 768 + col] = acc[nt][r];
                }
            }
        }
        gridbar(bar, eph); ++eph;

        // ======== stage 2: conv + SiLU + x_proj + dt (392 items, 4 tokens each) ====
        if (blockIdx.x < 392) {
            const float* cw   = conv_w  + (size_t)L * DINNER * 4;
            const float* cb   = conv_b  + (size_t)L * DINNER;
            const float* xpwl = xpwT    + (size_t)L * 384 * 44;
            const float* dtwl = dtwT    + (size_t)L * 12 * 384;
            const float* dtb  = dtb_all + (size_t)L * DINNER;
            int b = blockIdx.x / 49, c = blockIdx.x % 49;
            int l0 = c * 4;

            for (int idx = tid; idx < 7 * 384; idx += 256) {
                int t = idx / 384, d = idx % 384;
                int l = l0 - 3 + t;
                sm.cv.sxz[idx] = (l >= 0) ? xz[(size_t)(b * LSEQ + l) * 768 + d] : 0.f;
            }
            __syncthreads();

            for (int idx = tid; idx < 4 * 384; idx += 256) {
                int t = idx / 384, d = idx % 384;
                float4 w4 = *(const float4*)&cw[d * 4];
                float acc = cb[d]
                    + sm.cv.sxz[t * 384 + d]       * w4.x
                    + sm.cv.sxz[(t + 1) * 384 + d] * w4.y
                    + sm.cv.sxz[(t + 2) * 384 + d] * w4.z
                    + sm.cv.sxz[(t + 3) * 384 + d] * w4.w;
                float sig = 1.f / (1.f + __expf(-acc));
                float val = acc * sig;
                sm.cv.su[idx] = val;
                ubuf[(size_t)(b * LSEQ + l0 + t) * 384 + d] = val;
            }
            __syncthreads();

            {
                int wv = tid >> 6, e = tid & 63;
                if (e < 44) {
                    float a0 = 0.f, a1 = 0.f, a2 = 0.f, a3 = 0.f;
                    const float* ur = &sm.cv.su[wv * 384];
                    for (int j = 0; j < 384; j += 4) {
                        a0 += ur[j]     * xpwl[(j    ) * 44 + e];
                        a1 += ur[j + 1] * xpwl[(j + 1) * 44 + e];
                        a2 += ur[j + 2] * xpwl[(j + 2) * 44 + e];
                        a3 += ur[j + 3] * xpwl[(j + 3) * 44 + e];
                    }
                    sm.cv.sx[wv * 48 + e] = (a0 + a1) + (a2 + a3);
                }
            }
            __syncthreads();

            for (int idx = tid; idx < 4 * 384; idx += 256) {
                int t = idx / 384, d = idx % 384;
                float acc = dtb[d];
#pragma unroll
                for (int r = 0; r < DTRANK; ++r) acc += sm.cv.sx[t * 48 + r] * dtwl[r * 384 + d];
                float sp = (acc > 20.f) ? acc : log1pf(__expf(acc));
                dtbuf[(size_t)(b * LSEQ + l0 + t) * 384 + d] = sp;
            }
            if (tid < 128) {
                int t = tid >> 5, j = tid & 31;
                bcbuf[(size_t)(b * LSEQ + l0 + t) * 32 + j] = sm.cv.sx[t * 48 + 12 + j];
            }
        }
        gridbar(bar, eph); ++eph;

        // ======== stage 3: selective scan + gating (192 items) ========
        if (blockIdx.x < 192) {
            const float* Al = A_log + (size_t)L * DINNER * DSTATE;
            const float* Dl = D_param + (size_t)L * DINNER;
            int b  = blockIdx.x / 24;
            int dg = blockIdx.x % 24;
            int s = tid & 15, dl = tid >> 4;
            int d = dg * 16 + dl;
            float Ads = -expf(Al[d * DSTATE + s]);
            float Dd2 = Dl[dg * 16 + (tid & 15)];
            float h = 0.f;

            for (int c0 = 0; c0 < LSEQ; c0 += TCH) {
                if (tid < TCH * 4) {
                    int t = tid >> 2, j4 = (tid & 3) * 4;
                    size_t tok = (size_t)(b * LSEQ + c0 + t);
                    *(float4*)&sm.sc.sdt[t][j4] = *(const float4*)&dtbuf[tok * DINNER + dg * 16 + j4];
                    *(float4*)&sm.sc.su_[t][j4] = *(const float4*)&ubuf [tok * DINNER + dg * 16 + j4];
                    *(float4*)&sm.sc.sz_[t][j4] = *(const float4*)&xz   [tok * 768 + DINNER + dg * 16 + j4];
                    *(float4*)&sm.sc.sB_[t][j4] = *(const float4*)&bcbuf[tok * 32 + j4];
                    *(float4*)&sm.sc.sC_[t][j4] = *(const float4*)&bcbuf[tok * 32 + 16 + j4];
                }
                __syncthreads();

#pragma unroll 7
                for (int t = 0; t < TCH; ++t) {
                    float dtv = sm.sc.sdt[t][dl];
                    float uv  = sm.sc.su_[t][dl];
                    float Bv  = sm.sc.sB_[t][s];
                    float Cv  = sm.sc.sC_[t][s];
                    float dA  = __expf(dtv * Ads);
                    h = dA * h + (dtv * uv) * Bv;
                    sm.sc.sprod[t][dl * 17 + s] = h * Cv;
                }
                __syncthreads();

                for (int i = tid; i < TCH * 16; i += 256) {
                    int t = i >> 4, dl2 = i & 15;
                    float sum = 0.f;
#pragma unroll
                    for (int j = 0; j < 16; ++j) sum += sm.sc.sprod[t][dl2 * 17 + j];
                    float uv = sm.sc.su_[t][dl2];
                    float zv = sm.sc.sz_[t][dl2];
                    float sig = 1.f / (1.f + __expf(-zv));
                    ybf[(size_t)(b * LSEQ + c0 + t) * DINNER + dg * 16 + dl2] =
                        __float2bfloat16((sum + uv * Dd2) * (zv * sig));
                }
                __syncthreads();
            }
        }
        gridbar(bar, eph); ++eph;

        // ======== stage 4: out_proj + residual + LN (98 items, 16 rows each) =======
        if (blockIdx.x < 98) {
            int last = (L == DEPTH - 1);
            const float* lnw = last ? normf_w : norm_w + (size_t)(L + 1) * DMODEL;
            const float* lnb = last ? normf_b : norm_b + (size_t)(L + 1) * DMODEL;
            const short* Wb  = w_out + (size_t)L * DMODEL * DINNER;
            float* outf = last ? outF : nullptr;
            int m0 = blockIdx.x * 16;
            int wv = tid >> 6, lane = tid & 63;
            int fm = lane & 15, q = lane >> 4;
            int wrow = tid >> 2, kc = (tid & 3) * 8;
            if (tid < 192) {
                sm.gl.slw[tid] = lnw[tid];
                sm.gl.slb[tid] = lnb[tid];
            }
            const short* Ab = (const short*)ybf;
            floatx4 acc[3];
#pragma unroll
            for (int j = 0; j < 3; ++j) acc[j] = (floatx4){0.f, 0.f, 0.f, 0.f};

            short8 aR = {0,0,0,0,0,0,0,0};
            short8 wR[3];
            if (tid < 64) aR = *(const short8*)&Ab[(size_t)(m0 + (tid >> 2)) * DINNER + kc];
#pragma unroll
            for (int j = 0; j < 3; ++j)
                wR[j] = *(const short8*)&Wb[(size_t)(wrow + 64 * j) * DINNER + kc];

            for (int k0 = 0; k0 < DINNER; k0 += 32) {
                if (tid < 64) *(short8*)&sm.gl.As[(tid >> 2) * LDA + kc] = aR;
#pragma unroll
                for (int j = 0; j < 3; ++j)
                    *(short8*)&sm.gl.Ws[(wrow + 64 * j) * LDA + kc] = wR[j];
                __syncthreads();
                int kn = k0 + 32;
                if (kn < DINNER) {
                    if (tid < 64) aR = *(const short8*)&Ab[(size_t)(m0 + (tid >> 2)) * DINNER + kn + kc];
#pragma unroll
                    for (int j = 0; j < 3; ++j)
                        wR[j] = *(const short8*)&Wb[(size_t)(wrow + 64 * j) * DINNER + kn + kc];
                }
                short8 af = *(const short8*)&sm.gl.As[fm * LDA + q * 8];
#pragma unroll
                for (int j = 0; j < 3; ++j) {
                    int ct = wv * 3 + j;
                    short8 bf = *(const short8*)&sm.gl.Ws[(ct * 16 + fm) * LDA + q * 8];
                    acc[j] = __builtin_amdgcn_mfma_f32_16x16x32_bf16(af, bf, acc[j], 0, 0, 0);
                }
                __syncthreads();
            }

            float v[3][4];
#pragma unroll
            for (int r = 0; r < 4; ++r) {
                int m = m0 + q * 4 + r;
#pragma unroll
                for (int j = 0; j < 3; ++j) {
                    int col = (wv * 3 + j) * 16 + fm;
                    v[j][r] = acc[j][r] + residual[(size_t)m * DMODEL + col];
                }
            }
#pragma unroll
            for (int r = 0; r < 4; ++r) {
                int m = m0 + q * 4 + r;
#pragma unroll
                for (int j = 0; j < 3; ++j)
                    residual[(size_t)m * DMODEL + (wv * 3 + j) * 16 + fm] = v[j][r];
            }
#pragma unroll
            for (int r = 0; r < 4; ++r) {
                float s1 = v[0][r] + v[1][r] + v[2][r];
                float s2 = v[0][r]*v[0][r] + v[1][r]*v[1][r] + v[2][r]*v[2][r];
                s1 += __shfl_xor(s1, 1); s2 += __shfl_xor(s2, 1);
                s1 += __shfl_xor(s1, 2); s2 += __shfl_xor(s2, 2);
                s1 += __shfl_xor(s1, 4); s2 += __shfl_xor(s2, 4);
                s1 += __shfl_xor(s1, 8); s2 += __shfl_xor(s2, 8);
                if (fm == 0) { sm.gl.sS1[wv][q * 4 + r] = s1; sm.gl.sS2[wv][q * 4 + r] = s2; }
            }
            __syncthreads();
#pragma unroll
            for (int r = 0; r < 4; ++r) {
                int row = q * 4 + r;
                int m = m0 + row;
                float S1 = sm.gl.sS1[0][row] + sm.gl.sS1[1][row] + sm.gl.sS1[2][row] + sm.gl.sS1[3][row];
                float S2 = sm.gl.sS2[0][row] + sm.gl.sS2[1][row] + sm.gl.sS2[2][row] + sm.gl.sS2[3][row];
                float mean = S1 * (1.f / DMODEL);
                float var  = S2 * (1.f / DMODEL) - mean * mean;
                float rstd = rsqrtf(var + 1e-5f);
#pragma unroll
                for (int j = 0; j < 3; ++j) {
                    int col = (wv * 3 + j) * 16 + fm;
                    float o = (v[j][r] - mean) * rstd * sm.gl.slw[col] + sm.gl.slb[col];
                    if (outf) outf[(size_t)m * DMODEL + col] = o;
                    else      hn[(size_t)m * DMODEL + col] = __float2bfloat16(o);
                }
            }
        }
        gridbar(bar, eph); ++eph;
    }
}

// ---------------------------------------------------------------------------
extern "C" void kernel_launch(void* const* d_in, const int* in_sizes, int n_in,
                              void* d_out, int out_size, void* d_ws, size_t ws_size,
                              hipStream_t stream)
{
    const float* x         = (const float*)d_in[0];
    const float* pe_w      = (const float*)d_in[1];
    const float* pe_b      = (const float*)d_in[2];
    const float* norm_w    = (const float*)d_in[3];
    const float* norm_b    = (const float*)d_in[4];
    const float* in_proj_w = (const float*)d_in[5];
    const float* conv_w    = (const float*)d_in[6];
    const float* conv_b    = (const float*)d_in[7];
    const float* xproj_w   = (const float*)d_in[8];
    const float* dtproj_w  = (const float*)d_in[9];
    const float* dtproj_b  = (const float*)d_in[10];
    const float* A_log     = (const float*)d_in[11];
    const float* D_param   = (const float*)d_in[12];
    const float* outproj_w = (const float*)d_in[13];
    const float* normf_w   = (const float*)d_in[14];
    const float* normf_b   = (const float*)d_in[15];

    float* ws = (float*)d_ws;
    float* residual = ws;                       // 301056 f32
    float* xz       = residual + 301056;        // 1204224 f32
    float* ubuf     = xz + 1204224;             // 602112 f32
    float* dtbuf    = ubuf + 602112;            // 602112 f32
    float* bcbuf    = dtbuf + 602112;           // 50176 f32
    __hip_bfloat16* hn      = (__hip_bfloat16*)(ws + 2759680);  // 301056 bf16
    __hip_bfloat16* ybf     = (__hip_bfloat16*)(ws + 2910208);  // 602112 bf16
    __hip_bfloat16* patches = (__hip_bfloat16*)(ws + 3211264);  // 1204224 bf16
    short* w_in  = (short*)(ws + 3813376);      // 3538944 bf16
    short* w_out = (short*)(ws + 5582848);      // 1769472 bf16
    short* w_pe  = (short*)(ws + 6467584);      // 147456 bf16
    float* xpwT  = ws + 6541312;                // 405504 f32
    float* dtwT  = xpwT + 405504;               // 110592 f32
    unsigned* bar = (unsigned*)(ws + 7057408);  // 2048 u32 barrier state

    prep<<<12056, 256, 0, stream>>>(
        in_proj_w, outproj_w, pe_w, xproj_w, dtproj_w, x,
        w_in, w_out, w_pe, xpwT, dtwT, patches, bar);
    gemm_ln<768><<<98, 256, 0, stream>>>(
        patches, w_pe, pe_b, residual, hn, nullptr, norm_w, norm_b, 0);
    vim_mega<<<NB, 256, 0, stream>>>(
        w_in, conv_w, conv_b, xpwT, dtwT, dtproj_b, A_log, D_param, w_out,
        norm_w, norm_b, normf_w, normf_b, residual, xz, ubuf, dtbuf, bcbuf,
        hn, ybf, (float*)d_out, bar);
}

// Round 3
// 2041.978 us; speedup vs baseline: 1.8513x; 1.8513x over previous
//
#include <hip/hip_runtime.h>
#include <hip/hip_bf16.h>

// ---------------------------------------------------------------------------
// VisionMamba, round 14: per-XCD batch-pinned persistent kernel.
// B=8, L=196, D_MODEL=192, D_INNER=384, D_STATE=16, DT_RANK=12, DEPTH=24.
//
// R13 evidence: device-scope barriers (agent ACQ_REL -> wbl2+inv) destroyed
// all L2s 96x; 630MB L2-miss traffic at 170GB/s latency-bound = 3.7ms wall.
// R14: batches are independent and B == NXCD == 8. Pin batch b to XCD b via
// runtime XCC_ID claim (no mapping assumption): 1024 blocks @2/CU, first 64
// claimers per XCD become that batch's workers (resident by construction ->
// sub-barrier deadlock-free), rest exit. Intra-XCD barrier = vmcnt drain
// (write-through L1 -> shared L2 is the ordering point) + relaxed agent
// counter + L1-only buffer_inv. Working set/batch ~2.3MB fits 4MB L2.
// ---------------------------------------------------------------------------

#define NTOK   1568   // B * L
#define DMODEL 192
#define DINNER 384
#define DSTATE 16
#define DTRANK 12
#define DEPTH  24
#define LSEQ   196
#define TCH    49     // scan time-chunk (196 = 4*49)
#define LDA    40     // LDS row stride in bf16 elements (80B)
#define SPAD   272
#define NWORK  64     // workers per XCD (32 CU x 2 blocks)

typedef __attribute__((ext_vector_type(8))) short short8;
typedef __attribute__((ext_vector_type(4))) short short4v;
typedef __attribute__((ext_vector_type(4))) float floatx4;

__device__ inline short f2bf(float f) {
    __hip_bfloat16 h = __float2bfloat16(f);
    return *reinterpret_cast<short*>(&h);
}

// ---------------- LDS union for the mega-kernel stages ----------------
struct GiLDS { short As[64 * LDA]; short Ws[64 * LDA]; };                    // 10,240 B
struct CvLDS { float sxz[7 * 384]; float su[4 * 384]; float sx[4 * 48]; };   // 17,664 B
struct ScLDS {
    float sdt[TCH][16]; float su_[TCH][16]; float sz_[TCH][16];
    float sB_[TCH][16]; float sC_[TCH][16]; float sprod[TCH][SPAD];          // 68,992 B
};
struct GlLDS {
    short As[16 * LDA]; short Ws[192 * LDA];
    float slw[192]; float slb[192]; float sS1[4][16]; float sS2[4][16];      // 17,920 B
};
union MegaLDS { GiLDS gi; CvLDS cv; ScLDS sc; GlLDS gl; };

// ---------------- intra-XCD sub-barrier ----------------
// arr = this XCD's monotone arrival counter. target = NWORK * (#barriers so far).
// Release: first __syncthreads drains every wave's stores to L2 (write-through
// L1; L2 is the intra-XCD ordering point). Arrival/spin: relaxed agent atomics
// (no cache ops). Acquire: L1-only buffer_inv (no sc flags -> TCP invalidate,
// NOT the L2 wipe that agent-scope acquire emits).
__device__ __forceinline__ void xbar(unsigned* arr, unsigned target) {
    __syncthreads();
    if (threadIdx.x == 0) {
        asm volatile("s_waitcnt vmcnt(0)" ::: "memory");
        __hip_atomic_fetch_add(arr, 1u, __ATOMIC_RELAXED, __HIP_MEMORY_SCOPE_AGENT);
        unsigned tmo = 0;
        while (__hip_atomic_load(arr, __ATOMIC_RELAXED, __HIP_MEMORY_SCOPE_AGENT) < target) {
            __builtin_amdgcn_s_sleep(2);
            if (++tmo > 200000u) break;   // failsafe: wrong answer, not a hang
        }
    }
    __syncthreads();
    asm volatile("buffer_inv" ::: "memory");
}

// ---------------- merged pre-stage: weight cvt + transposes + im2col + bar zero --------
#define PR1 884736
#define PR2 1327104   // +442368
#define PR3 1363968   // +36864
#define PR4 1769472   // +405504
#define PR5 1880064   // +110592
#define PR6 3084288   // +1204224
#define PR7 3086336   // +2048 (barrier/claim state zero)
__global__ __launch_bounds__(256) void prep(
    const float* __restrict__ inw, const float* __restrict__ outw,
    const float* __restrict__ pew, const float* __restrict__ xpw,
    const float* __restrict__ dtw, const float* __restrict__ x,
    short* __restrict__ w_in, short* __restrict__ w_out,
    short* __restrict__ w_pe, float* __restrict__ xpwT,
    float* __restrict__ dtwT, __hip_bfloat16* __restrict__ patches,
    unsigned* __restrict__ bar)
{
    int idx = blockIdx.x * 256 + threadIdx.x;
    if (idx < PR3) {
        float4 v; short* dst;
        if (idx < PR1)      { v = ((const float4*)inw)[idx];        dst = w_in  + (size_t)idx * 4; }
        else if (idx < PR2) { int i = idx - PR1; v = ((const float4*)outw)[i]; dst = w_out + (size_t)i * 4; }
        else                { int i = idx - PR2; v = ((const float4*)pew)[i];  dst = w_pe  + (size_t)i * 4; }
        short4v o;
        o[0] = f2bf(v.x); o[1] = f2bf(v.y); o[2] = f2bf(v.z); o[3] = f2bf(v.w);
        *(short4v*)dst = o;
    } else if (idx < PR4) {
        int i = idx - PR3;                    // xpwT[layer][k][e] = xpw[layer][e][k]
        int layer = i / 16896, rem = i % 16896;
        int k = rem / 44, e = rem % 44;
        xpwT[i] = xpw[(size_t)layer * 16896 + e * 384 + k];
    } else if (idx < PR5) {
        int i = idx - PR4;                    // dtwT[layer][r][d] = dtw[layer][d][r]
        int layer = i / 4608, rem = i % 4608;
        int r = rem / 384, d = rem % 384;
        dtwT[i] = dtw[(size_t)layer * 4608 + d * 12 + r];
    } else if (idx < PR6) {
        int i = idx - PR5;                    // im2col
        int tok = i / 768, e = i % 768;
        int b = tok / LSEQ, l = tok % LSEQ;
        int py = l / 14, px = l % 14;
        int ic = e >> 8, rem = e & 255, ky = rem >> 4, kx = rem & 15;
        patches[i] = __float2bfloat16(x[((b * 3 + ic) * 224 + py * 16 + ky) * 224 + px * 16 + kx]);
    } else if (idx < PR7) {
        bar[idx - PR6] = 0u;
    }
}

// ---------------- standalone gemm_ln (used once for patch-embed + LN0) ----------------
template<int K>
__global__ __launch_bounds__(256) void gemm_ln(
    const __hip_bfloat16* __restrict__ A, const short* __restrict__ Wb,
    const float* __restrict__ bias, float* __restrict__ residual,
    __hip_bfloat16* __restrict__ hn, float* __restrict__ outf,
    const float* __restrict__ lnw, const float* __restrict__ lnb,
    int accumulate)
{
    __shared__ short As[16 * LDA];
    __shared__ short Ws[192 * LDA];
    __shared__ float slw[192], slb[192], sbias[192];
    __shared__ float sS1[4][16], sS2[4][16];
    int tid = threadIdx.x;
    int m0 = blockIdx.x * 16;
    int wv = tid >> 6, lane = tid & 63;
    int fm = lane & 15, q = lane >> 4;
    int wrow = tid >> 2, kc = (tid & 3) * 8;
    if (tid < 192) {
        slw[tid] = lnw[tid];
        slb[tid] = lnb[tid];
        sbias[tid] = bias ? bias[tid] : 0.f;
    }
    const short* Ab = (const short*)A;
    floatx4 acc[3];
#pragma unroll
    for (int j = 0; j < 3; ++j) acc[j] = (floatx4){0.f, 0.f, 0.f, 0.f};

    short8 aR = {0,0,0,0,0,0,0,0};
    short8 wR[3];
    if (tid < 64) aR = *(const short8*)&Ab[(size_t)(m0 + (tid >> 2)) * K + kc];
#pragma unroll
    for (int j = 0; j < 3; ++j)
        wR[j] = *(const short8*)&Wb[(size_t)(wrow + 64 * j) * K + kc];

    for (int k0 = 0; k0 < K; k0 += 32) {
        if (tid < 64) *(short8*)&As[(tid >> 2) * LDA + kc] = aR;
#pragma unroll
        for (int j = 0; j < 3; ++j)
            *(short8*)&Ws[(wrow + 64 * j) * LDA + kc] = wR[j];
        __syncthreads();
        int kn = k0 + 32;
        if (kn < K) {
            if (tid < 64) aR = *(const short8*)&Ab[(size_t)(m0 + (tid >> 2)) * K + kn + kc];
#pragma unroll
            for (int j = 0; j < 3; ++j)
                wR[j] = *(const short8*)&Wb[(size_t)(wrow + 64 * j) * K + kn + kc];
        }
        short8 af = *(const short8*)&As[fm * LDA + q * 8];
#pragma unroll
        for (int j = 0; j < 3; ++j) {
            int ct = wv * 3 + j;
            short8 bf = *(const short8*)&Ws[(ct * 16 + fm) * LDA + q * 8];
            acc[j] = __builtin_amdgcn_mfma_f32_16x16x32_bf16(af, bf, acc[j], 0, 0, 0);
        }
        __syncthreads();
    }

    float v[3][4];
#pragma unroll
    for (int r = 0; r < 4; ++r) {
        int m = m0 + q * 4 + r;
#pragma unroll
        for (int j = 0; j < 3; ++j) {
            int col = (wv * 3 + j) * 16 + fm;
            float t = acc[j][r] + sbias[col];
            if (accumulate) t += residual[(size_t)m * DMODEL + col];
            v[j][r] = t;
        }
    }
#pragma unroll
    for (int r = 0; r < 4; ++r) {
        int m = m0 + q * 4 + r;
#pragma unroll
        for (int j = 0; j < 3; ++j)
            residual[(size_t)m * DMODEL + (wv * 3 + j) * 16 + fm] = v[j][r];
    }
#pragma unroll
    for (int r = 0; r < 4; ++r) {
        float s1 = v[0][r] + v[1][r] + v[2][r];
        float s2 = v[0][r]*v[0][r] + v[1][r]*v[1][r] + v[2][r]*v[2][r];
        s1 += __shfl_xor(s1, 1); s2 += __shfl_xor(s2, 1);
        s1 += __shfl_xor(s1, 2); s2 += __shfl_xor(s2, 2);
        s1 += __shfl_xor(s1, 4); s2 += __shfl_xor(s2, 4);
        s1 += __shfl_xor(s1, 8); s2 += __shfl_xor(s2, 8);
        if (fm == 0) { sS1[wv][q * 4 + r] = s1; sS2[wv][q * 4 + r] = s2; }
    }
    __syncthreads();
#pragma unroll
    for (int r = 0; r < 4; ++r) {
        int row = q * 4 + r;
        int m = m0 + row;
        float S1 = sS1[0][row] + sS1[1][row] + sS1[2][row] + sS1[3][row];
        float S2 = sS2[0][row] + sS2[1][row] + sS2[2][row] + sS2[3][row];
        float mean = S1 * (1.f / DMODEL);
        float var  = S2 * (1.f / DMODEL) - mean * mean;
        float rstd = rsqrtf(var + 1e-5f);
#pragma unroll
        for (int j = 0; j < 3; ++j) {
            int col = (wv * 3 + j) * 16 + fm;
            float o = (v[j][r] - mean) * rstd * slw[col] + slb[col];
            if (outf) outf[(size_t)m * DMODEL + col] = o;
            else      hn[(size_t)m * DMODEL + col] = __float2bfloat16(o);
        }
    }
}

// ---------------- per-XCD batch-pinned persistent kernel ----------------
// bar layout: bar[x*32] = XCD x arrival counter; bar[256 + x*32] = claim counter.
__global__ __launch_bounds__(256, 2) void vim_mega(
    const short* __restrict__ w_in, const float* __restrict__ conv_w,
    const float* __restrict__ conv_b, const float* __restrict__ xpwT,
    const float* __restrict__ dtwT, const float* __restrict__ dtb_all,
    const float* __restrict__ A_log, const float* __restrict__ D_param,
    const short* __restrict__ w_out, const float* __restrict__ norm_w,
    const float* __restrict__ norm_b, const float* __restrict__ normf_w,
    const float* __restrict__ normf_b, float* __restrict__ residual,
    float* __restrict__ xz, float* __restrict__ ubuf,
    float* __restrict__ dtbuf, float* __restrict__ bcbuf,
    __hip_bfloat16* __restrict__ hn, __hip_bfloat16* __restrict__ ybf,
    float* __restrict__ outF, unsigned* __restrict__ bar)
{
    __shared__ MegaLDS sm;
    __shared__ int s_role;
    int tid = threadIdx.x;

    // claim a worker slot on MY physical XCD (HW_REG_XCC_ID, id=20, sz=32)
    if (tid == 0) {
        unsigned xcd = __builtin_amdgcn_s_getreg(20 | (0 << 6) | (31 << 11)) & 7u;
        unsigned slot = __hip_atomic_fetch_add(&bar[256 + xcd * 32], 1u,
                          __ATOMIC_RELAXED, __HIP_MEMORY_SCOPE_AGENT);
        s_role = (slot < NWORK) ? (int)(xcd * NWORK + slot) : -1;
    }
    __syncthreads();
    int role = s_role;
    if (role < 0) return;                 // surplus block: free the CU slot
    int myb = role >> 6;                  // batch == XCD
    int it  = role & 63;                  // worker index within sub-grid
    unsigned* arr = &bar[myb * 32];
    unsigned nbar = 0;
    const size_t tok0 = (size_t)myb * LSEQ;

    for (int L = 0; L < DEPTH; ++L) {
        // ======== stage 1: xz[b] = hn[b] @ w_in^T  (48 items: 4 m-tiles x 12 n-tiles)
        if (it < 48) {
            const short* wi = w_in + (size_t)L * 768 * DMODEL;
            int m0 = (it / 12) * 64, n0 = (it % 12) * 64;
            int wv = tid >> 6, lane = tid & 63;
            int fm = lane & 15, q = lane >> 4;
            int row = tid >> 2, kc = (tid & 3) * 8;
            const short* Ab = (const short*)hn;
            floatx4 acc[4];
#pragma unroll
            for (int nt = 0; nt < 4; ++nt) acc[nt] = (floatx4){0.f, 0.f, 0.f, 0.f};
#pragma unroll
            for (int k0 = 0; k0 < DMODEL; k0 += 32) {
                {
                    int lm = m0 + row;
                    short8 v = {0,0,0,0,0,0,0,0};
                    if (lm < LSEQ) v = *(const short8*)&Ab[(tok0 + lm) * DMODEL + k0 + kc];
                    *(short8*)&sm.gi.As[row * LDA + kc] = v;
                }
                {
                    short8 w = *(const short8*)&wi[(size_t)(n0 + row) * DMODEL + k0 + kc];
                    *(short8*)&sm.gi.Ws[row * LDA + kc] = w;
                }
                __syncthreads();
                short8 af = *(const short8*)&sm.gi.As[(wv * 16 + fm) * LDA + q * 8];
#pragma unroll
                for (int nt = 0; nt < 4; ++nt) {
                    short8 bf = *(const short8*)&sm.gi.Ws[(nt * 16 + fm) * LDA + q * 8];
                    acc[nt] = __builtin_amdgcn_mfma_f32_16x16x32_bf16(af, bf, acc[nt], 0, 0, 0);
                }
                __syncthreads();
            }
#pragma unroll
            for (int nt = 0; nt < 4; ++nt) {
                int col = n0 + nt * 16 + fm;
#pragma unroll
                for (int r = 0; r < 4; ++r) {
                    int lm = m0 + wv * 16 + q * 4 + r;
                    if (lm < LSEQ) xz[(tok0 + lm) * 768 + col] = acc[nt][r];
                }
            }
        }
        ++nbar; xbar(arr, NWORK * nbar);

        // ======== stage 2: conv + SiLU + x_proj + dt  (49 items, 4 tokens each)
        if (it < 49) {
            const float* cw   = conv_w  + (size_t)L * DINNER * 4;
            const float* cb   = conv_b  + (size_t)L * DINNER;
            const float* xpwl = xpwT    + (size_t)L * 384 * 44;
            const float* dtwl = dtwT    + (size_t)L * 12 * 384;
            const float* dtb  = dtb_all + (size_t)L * DINNER;
            int l0 = it * 4;

            for (int idx = tid; idx < 7 * 384; idx += 256) {
                int t = idx / 384, d = idx % 384;
                int l = l0 - 3 + t;
                sm.cv.sxz[idx] = (l >= 0) ? xz[(tok0 + l) * 768 + d] : 0.f;
            }
            __syncthreads();

            for (int idx = tid; idx < 4 * 384; idx += 256) {
                int t = idx / 384, d = idx % 384;
                float4 w4 = *(const float4*)&cw[d * 4];
                float acc = cb[d]
                    + sm.cv.sxz[t * 384 + d]       * w4.x
                    + sm.cv.sxz[(t + 1) * 384 + d] * w4.y
                    + sm.cv.sxz[(t + 2) * 384 + d] * w4.z
                    + sm.cv.sxz[(t + 3) * 384 + d] * w4.w;
                float sig = 1.f / (1.f + __expf(-acc));
                float val = acc * sig;
                sm.cv.su[idx] = val;
                ubuf[(tok0 + l0 + t) * 384 + d] = val;
            }
            __syncthreads();

            {
                int wv = tid >> 6, e = tid & 63;
                if (e < 44) {
                    float a0 = 0.f, a1 = 0.f, a2 = 0.f, a3 = 0.f;
                    const float* ur = &sm.cv.su[wv * 384];
                    for (int j = 0; j < 384; j += 4) {
                        a0 += ur[j]     * xpwl[(j    ) * 44 + e];
                        a1 += ur[j + 1] * xpwl[(j + 1) * 44 + e];
                        a2 += ur[j + 2] * xpwl[(j + 2) * 44 + e];
                        a3 += ur[j + 3] * xpwl[(j + 3) * 44 + e];
                    }
                    sm.cv.sx[wv * 48 + e] = (a0 + a1) + (a2 + a3);
                }
            }
            __syncthreads();

            for (int idx = tid; idx < 4 * 384; idx += 256) {
                int t = idx / 384, d = idx % 384;
                float acc = dtb[d];
#pragma unroll
                for (int r = 0; r < DTRANK; ++r) acc += sm.cv.sx[t * 48 + r] * dtwl[r * 384 + d];
                float sp = (acc > 20.f) ? acc : log1pf(__expf(acc));
                dtbuf[(tok0 + l0 + t) * 384 + d] = sp;
            }
            if (tid < 128) {
                int t = tid >> 5, j = tid & 31;
                bcbuf[(tok0 + l0 + t) * 32 + j] = sm.cv.sx[t * 48 + 12 + j];
            }
        }
        ++nbar; xbar(arr, NWORK * nbar);

        // ======== stage 3: selective scan + gating  (24 items = d-groups)
        if (it < 24) {
            const float* Al = A_log + (size_t)L * DINNER * DSTATE;
            const float* Dl = D_param + (size_t)L * DINNER;
            int dg = it;
            int s = tid & 15, dl = tid >> 4;
            int d = dg * 16 + dl;
            float Ads = -expf(Al[d * DSTATE + s]);
            float Dd2 = Dl[dg * 16 + (tid & 15)];
            float h = 0.f;

            for (int c0 = 0; c0 < LSEQ; c0 += TCH) {
                if (tid < TCH * 4) {
                    int t = tid >> 2, j4 = (tid & 3) * 4;
                    size_t tok = tok0 + c0 + t;
                    *(float4*)&sm.sc.sdt[t][j4] = *(const float4*)&dtbuf[tok * DINNER + dg * 16 + j4];
                    *(float4*)&sm.sc.su_[t][j4] = *(const float4*)&ubuf [tok * DINNER + dg * 16 + j4];
                    *(float4*)&sm.sc.sz_[t][j4] = *(const float4*)&xz   [tok * 768 + DINNER + dg * 16 + j4];
                    *(float4*)&sm.sc.sB_[t][j4] = *(const float4*)&bcbuf[tok * 32 + j4];
                    *(float4*)&sm.sc.sC_[t][j4] = *(const float4*)&bcbuf[tok * 32 + 16 + j4];
                }
                __syncthreads();

#pragma unroll 7
                for (int t = 0; t < TCH; ++t) {
                    float dtv = sm.sc.sdt[t][dl];
                    float uv  = sm.sc.su_[t][dl];
                    float Bv  = sm.sc.sB_[t][s];
                    float Cv  = sm.sc.sC_[t][s];
                    float dA  = __expf(dtv * Ads);
                    h = dA * h + (dtv * uv) * Bv;
                    sm.sc.sprod[t][dl * 17 + s] = h * Cv;
                }
                __syncthreads();

                for (int i = tid; i < TCH * 16; i += 256) {
                    int t = i >> 4, dl2 = i & 15;
                    float sum = 0.f;
#pragma unroll
                    for (int j = 0; j < 16; ++j) sum += sm.sc.sprod[t][dl2 * 17 + j];
                    float uv = sm.sc.su_[t][dl2];
                    float zv = sm.sc.sz_[t][dl2];
                    float sig = 1.f / (1.f + __expf(-zv));
                    ybf[(tok0 + c0 + t) * DINNER + dg * 16 + dl2] =
                        __float2bfloat16((sum + uv * Dd2) * (zv * sig));
                }
                __syncthreads();
            }
        }
        ++nbar; xbar(arr, NWORK * nbar);

        // ======== stage 4: out_proj + residual + LN  (13 items, 16 rows each)
        if (it < 13) {
            int last = (L == DEPTH - 1);
            const float* lnw = last ? normf_w : norm_w + (size_t)(L + 1) * DMODEL;
            const float* lnb = last ? normf_b : norm_b + (size_t)(L + 1) * DMODEL;
            const short* Wb  = w_out + (size_t)L * DMODEL * DINNER;
            float* outf = last ? outF : nullptr;
            int m0 = it * 16;
            int wv = tid >> 6, lane = tid & 63;
            int fm = lane & 15, q = lane >> 4;
            int wrow = tid >> 2, kc = (tid & 3) * 8;
            if (tid < 192) {
                sm.gl.slw[tid] = lnw[tid];
                sm.gl.slb[tid] = lnb[tid];
            }
            const short* Ab = (const short*)ybf;
            floatx4 acc[3];
#pragma unroll
            for (int j = 0; j < 3; ++j) acc[j] = (floatx4){0.f, 0.f, 0.f, 0.f};

            int lmA = m0 + (tid >> 2); if (lmA > LSEQ - 1) lmA = LSEQ - 1;   // clamp tail
            short8 aR = {0,0,0,0,0,0,0,0};
            short8 wR[3];
            if (tid < 64) aR = *(const short8*)&Ab[(tok0 + lmA) * DINNER + kc];
#pragma unroll
            for (int j = 0; j < 3; ++j)
                wR[j] = *(const short8*)&Wb[(size_t)(wrow + 64 * j) * DINNER + kc];

            for (int k0 = 0; k0 < DINNER; k0 += 32) {
                if (tid < 64) *(short8*)&sm.gl.As[(tid >> 2) * LDA + kc] = aR;
#pragma unroll
                for (int j = 0; j < 3; ++j)
                    *(short8*)&sm.gl.Ws[(wrow + 64 * j) * LDA + kc] = wR[j];
                __syncthreads();
                int kn = k0 + 32;
                if (kn < DINNER) {
                    if (tid < 64) aR = *(const short8*)&Ab[(tok0 + lmA) * DINNER + kn + kc];
#pragma unroll
                    for (int j = 0; j < 3; ++j)
                        wR[j] = *(const short8*)&Wb[(size_t)(wrow + 64 * j) * DINNER + kn + kc];
                }
                short8 af = *(const short8*)&sm.gl.As[fm * LDA + q * 8];
#pragma unroll
                for (int j = 0; j < 3; ++j) {
                    int ct = wv * 3 + j;
                    short8 bf = *(const short8*)&sm.gl.Ws[(ct * 16 + fm) * LDA + q * 8];
                    acc[j] = __builtin_amdgcn_mfma_f32_16x16x32_bf16(af, bf, acc[j], 0, 0, 0);
                }
                __syncthreads();
            }

            float v[3][4];
#pragma unroll
            for (int r = 0; r < 4; ++r) {
                int lm = m0 + q * 4 + r;
                int ok = lm < LSEQ;
#pragma unroll
                for (int j = 0; j < 3; ++j) {
                    int col = (wv * 3 + j) * 16 + fm;
                    v[j][r] = acc[j][r] + (ok ? residual[(tok0 + lm) * DMODEL + col] : 0.f);
                }
            }
#pragma unroll
            for (int r = 0; r < 4; ++r) {
                int lm = m0 + q * 4 + r;
                if (lm < LSEQ) {
#pragma unroll
                    for (int j = 0; j < 3; ++j)
                        residual[(tok0 + lm) * DMODEL + (wv * 3 + j) * 16 + fm] = v[j][r];
                }
            }
#pragma unroll
            for (int r = 0; r < 4; ++r) {
                float s1 = v[0][r] + v[1][r] + v[2][r];
                float s2 = v[0][r]*v[0][r] + v[1][r]*v[1][r] + v[2][r]*v[2][r];
                s1 += __shfl_xor(s1, 1); s2 += __shfl_xor(s2, 1);
                s1 += __shfl_xor(s1, 2); s2 += __shfl_xor(s2, 2);
                s1 += __shfl_xor(s1, 4); s2 += __shfl_xor(s2, 4);
                s1 += __shfl_xor(s1, 8); s2 += __shfl_xor(s2, 8);
                if (fm == 0) { sm.gl.sS1[wv][q * 4 + r] = s1; sm.gl.sS2[wv][q * 4 + r] = s2; }
            }
            __syncthreads();
#pragma unroll
            for (int r = 0; r < 4; ++r) {
                int row = q * 4 + r;
                int lm = m0 + row;
                float S1 = sm.gl.sS1[0][row] + sm.gl.sS1[1][row] + sm.gl.sS1[2][row] + sm.gl.sS1[3][row];
                float S2 = sm.gl.sS2[0][row] + sm.gl.sS2[1][row] + sm.gl.sS2[2][row] + sm.gl.sS2[3][row];
                float mean = S1 * (1.f / DMODEL);
                float var  = S2 * (1.f / DMODEL) - mean * mean;
                float rstd = rsqrtf(var + 1e-5f);
                if (lm < LSEQ) {
#pragma unroll
                    for (int j = 0; j < 3; ++j) {
                        int col = (wv * 3 + j) * 16 + fm;
                        float o = (v[j][r] - mean) * rstd * sm.gl.slw[col] + sm.gl.slb[col];
                        if (outf) outf[(tok0 + lm) * DMODEL + col] = o;
                        else      hn[(tok0 + lm) * DMODEL + col] = __float2bfloat16(o);
                    }
                }
            }
        }
        ++nbar; xbar(arr, NWORK * nbar);
    }
}

// ---------------------------------------------------------------------------
extern "C" void kernel_launch(void* const* d_in, const int* in_sizes, int n_in,
                              void* d_out, int out_size, void* d_ws, size_t ws_size,
                              hipStream_t stream)
{
    const float* x         = (const float*)d_in[0];
    const float* pe_w      = (const float*)d_in[1];
    const float* pe_b      = (const float*)d_in[2];
    const float* norm_w    = (const float*)d_in[3];
    const float* norm_b    = (const float*)d_in[4];
    const float* in_proj_w = (const float*)d_in[5];
    const float* conv_w    = (const float*)d_in[6];
    const float* conv_b    = (const float*)d_in[7];
    const float* xproj_w   = (const float*)d_in[8];
    const float* dtproj_w  = (const float*)d_in[9];
    const float* dtproj_b  = (const float*)d_in[10];
    const float* A_log     = (const float*)d_in[11];
    const float* D_param   = (const float*)d_in[12];
    const float* outproj_w = (const float*)d_in[13];
    const float* normf_w   = (const float*)d_in[14];
    const float* normf_b   = (const float*)d_in[15];

    float* ws = (float*)d_ws;
    float* residual = ws;                       // 301056 f32
    float* xz       = residual + 301056;        // 1204224 f32
    float* ubuf     = xz + 1204224;             // 602112 f32
    float* dtbuf    = ubuf + 602112;            // 602112 f32
    float* bcbuf    = dtbuf + 602112;           // 50176 f32
    __hip_bfloat16* hn      = (__hip_bfloat16*)(ws + 2759680);  // 301056 bf16
    __hip_bfloat16* ybf     = (__hip_bfloat16*)(ws + 2910208);  // 602112 bf16
    __hip_bfloat16* patches = (__hip_bfloat16*)(ws + 3211264);  // 1204224 bf16
    short* w_in  = (short*)(ws + 3813376);      // 3538944 bf16
    short* w_out = (short*)(ws + 5582848);      // 1769472 bf16
    short* w_pe  = (short*)(ws + 6467584);      // 147456 bf16
    float* xpwT  = ws + 6541312;                // 405504 f32
    float* dtwT  = xpwT + 405504;               // 110592 f32
    unsigned* bar = (unsigned*)(ws + 7057408);  // 2048 u32 barrier/claim state

    prep<<<12056, 256, 0, stream>>>(
        in_proj_w, outproj_w, pe_w, xproj_w, dtproj_w, x,
        w_in, w_out, w_pe, xpwT, dtwT, patches, bar);
    gemm_ln<768><<<98, 256, 0, stream>>>(
        patches, w_pe, pe_b, residual, hn, nullptr, norm_w, norm_b, 0);
    vim_mega<<<1024, 256, 0, stream>>>(
        w_in, conv_w, conv_b, xpwT, dtwT, dtproj_b, A_log, D_param, w_out,
        norm_w, norm_b, normf_w, normf_b, residual, xz, ubuf, dtbuf, bcbuf,
        hn, ybf, (float*)d_out, bar);
}

// Round 4
// 1915.580 us; speedup vs baseline: 1.9735x; 1.0660x over previous
//
#include <hip/hip_runtime.h>
#include <hip/hip_bf16.h>

// ---------------------------------------------------------------------------
// VisionMamba, round 15: back to split pipeline (R12 = 1421us verified best),
// with gemm_in + conv + silu + x_proj + dt fused into ONE kernel per layer.
// B=8, L=196, D_MODEL=192, D_INNER=384, D_STATE=16, DT_RANK=12, DEPTH=24.
//
// R13/R14 evidence: persistent+barrier variants (3780, 2042us) lose to the
// split pipeline — barrier cost (serialized same-line agent atomics, low TLP,
// per-XCD weight refetch) > the ~7us/boundary launch gaps they remove.
// R15: cut dispatches 4->3 per layer instead. Each fused block owns 8 tokens
// x all 768 in_proj outputs: 16-row MFMA tile INCLUDES the 3 halo rows
// (rows g0-3..g0+7), W streamed via LDS in K-slices; conv taps masked by
// l%196 (handles batch seams); x_proj reads full rows from LDS. xin never
// hits global; xz f32 replaced by z-half-only zbuf (saves ~7MB/layer L2).
// scan + gemm_ln bodies unchanged (verified).
// ---------------------------------------------------------------------------

#define NTOK   1568   // B * L
#define DMODEL 192
#define DINNER 384
#define DSTATE 16
#define DTRANK 12
#define DEPTH  24
#define LSEQ   196
#define TCH    49     // scan time-chunk (196 = 4*49)
#define LDA    40     // LDS row stride in bf16 elements (80B)
#define ALD    200    // fused-A A-tile row stride (192 + 8 pad)
#define SPAD   272

typedef __attribute__((ext_vector_type(8))) short short8;
typedef __attribute__((ext_vector_type(4))) short short4v;
typedef __attribute__((ext_vector_type(4))) float floatx4;

__device__ inline short f2bf(float f) {
    __hip_bfloat16 h = __float2bfloat16(f);
    return *reinterpret_cast<short*>(&h);
}

// ---------------- merged pre-stage: weight cvt + transposes + im2col ----------------
#define PR1 884736
#define PR2 1327104   // +442368
#define PR3 1363968   // +36864
#define PR4 1769472   // +405504
#define PR5 1880064   // +110592
#define PR6 3084288   // +1204224
__global__ __launch_bounds__(256) void prep(
    const float* __restrict__ inw, const float* __restrict__ outw,
    const float* __restrict__ pew, const float* __restrict__ xpw,
    const float* __restrict__ dtw, const float* __restrict__ x,
    short* __restrict__ w_in, short* __restrict__ w_out,
    short* __restrict__ w_pe, float* __restrict__ xpwT,
    float* __restrict__ dtwT, __hip_bfloat16* __restrict__ patches)
{
    int idx = blockIdx.x * 256 + threadIdx.x;
    if (idx < PR3) {
        float4 v; short* dst;
        if (idx < PR1)      { v = ((const float4*)inw)[idx];        dst = w_in  + (size_t)idx * 4; }
        else if (idx < PR2) { int i = idx - PR1; v = ((const float4*)outw)[i]; dst = w_out + (size_t)i * 4; }
        else                { int i = idx - PR2; v = ((const float4*)pew)[i];  dst = w_pe  + (size_t)i * 4; }
        short4v o;
        o[0] = f2bf(v.x); o[1] = f2bf(v.y); o[2] = f2bf(v.z); o[3] = f2bf(v.w);
        *(short4v*)dst = o;
    } else if (idx < PR4) {
        int i = idx - PR3;                    // xpwT[layer][k][e] = xpw[layer][e][k]
        int layer = i / 16896, rem = i % 16896;
        int k = rem / 44, e = rem % 44;
        xpwT[i] = xpw[(size_t)layer * 16896 + e * 384 + k];
    } else if (idx < PR5) {
        int i = idx - PR4;                    // dtwT[layer][r][d] = dtw[layer][d][r]
        int layer = i / 4608, rem = i % 4608;
        int r = rem / 384, d = rem % 384;
        dtwT[i] = dtw[(size_t)layer * 4608 + d * 12 + r];
    } else if (idx < PR6) {
        int i = idx - PR5;                    // im2col
        int tok = i / 768, e = i % 768;
        int b = tok / LSEQ, l = tok % LSEQ;
        int py = l / 14, px = l % 14;
        int ic = e >> 8, rem = e & 255, ky = rem >> 4, kx = rem & 15;
        patches[i] = __float2bfloat16(x[((b * 3 + ic) * 224 + py * 16 + ky) * 224 + px * 16 + kx]);
    }
}

// ---------------- gemm_ln: 16-row tiles, pipelined LDS, fused residual+LN ----------------
template<int K>
__global__ __launch_bounds__(256) void gemm_ln(
    const __hip_bfloat16* __restrict__ A, const short* __restrict__ Wb,
    const float* __restrict__ bias, float* __restrict__ residual,
    __hip_bfloat16* __restrict__ hn, float* __restrict__ outf,
    const float* __restrict__ lnw, const float* __restrict__ lnb,
    int accumulate)
{
    __shared__ short As[16 * LDA];
    __shared__ short Ws[192 * LDA];
    __shared__ float slw[192], slb[192], sbias[192];
    __shared__ float sS1[4][16], sS2[4][16];
    int tid = threadIdx.x;
    int m0 = blockIdx.x * 16;
    int wv = tid >> 6, lane = tid & 63;
    int fm = lane & 15, q = lane >> 4;
    int wrow = tid >> 2, kc = (tid & 3) * 8;
    if (tid < 192) {
        slw[tid] = lnw[tid];
        slb[tid] = lnb[tid];
        sbias[tid] = bias ? bias[tid] : 0.f;
    }
    const short* Ab = (const short*)A;
    floatx4 acc[3];
#pragma unroll
    for (int j = 0; j < 3; ++j) acc[j] = (floatx4){0.f, 0.f, 0.f, 0.f};

    short8 aR = {0,0,0,0,0,0,0,0};
    short8 wR[3];
    if (tid < 64) aR = *(const short8*)&Ab[(size_t)(m0 + (tid >> 2)) * K + kc];
#pragma unroll
    for (int j = 0; j < 3; ++j)
        wR[j] = *(const short8*)&Wb[(size_t)(wrow + 64 * j) * K + kc];

    for (int k0 = 0; k0 < K; k0 += 32) {
        if (tid < 64) *(short8*)&As[(tid >> 2) * LDA + kc] = aR;
#pragma unroll
        for (int j = 0; j < 3; ++j)
            *(short8*)&Ws[(wrow + 64 * j) * LDA + kc] = wR[j];
        __syncthreads();
        int kn = k0 + 32;
        if (kn < K) {
            if (tid < 64) aR = *(const short8*)&Ab[(size_t)(m0 + (tid >> 2)) * K + kn + kc];
#pragma unroll
            for (int j = 0; j < 3; ++j)
                wR[j] = *(const short8*)&Wb[(size_t)(wrow + 64 * j) * K + kn + kc];
        }
        short8 af = *(const short8*)&As[fm * LDA + q * 8];
#pragma unroll
        for (int j = 0; j < 3; ++j) {
            int ct = wv * 3 + j;
            short8 bf = *(const short8*)&Ws[(ct * 16 + fm) * LDA + q * 8];
            acc[j] = __builtin_amdgcn_mfma_f32_16x16x32_bf16(af, bf, acc[j], 0, 0, 0);
        }
        __syncthreads();
    }

    float v[3][4];
#pragma unroll
    for (int r = 0; r < 4; ++r) {
        int m = m0 + q * 4 + r;
#pragma unroll
        for (int j = 0; j < 3; ++j) {
            int col = (wv * 3 + j) * 16 + fm;
            float t = acc[j][r] + sbias[col];
            if (accumulate) t += residual[(size_t)m * DMODEL + col];
            v[j][r] = t;
        }
    }
#pragma unroll
    for (int r = 0; r < 4; ++r) {
        int m = m0 + q * 4 + r;
#pragma unroll
        for (int j = 0; j < 3; ++j)
            residual[(size_t)m * DMODEL + (wv * 3 + j) * 16 + fm] = v[j][r];
    }
#pragma unroll
    for (int r = 0; r < 4; ++r) {
        float s1 = v[0][r] + v[1][r] + v[2][r];
        float s2 = v[0][r]*v[0][r] + v[1][r]*v[1][r] + v[2][r]*v[2][r];
        s1 += __shfl_xor(s1, 1); s2 += __shfl_xor(s2, 1);
        s1 += __shfl_xor(s1, 2); s2 += __shfl_xor(s2, 2);
        s1 += __shfl_xor(s1, 4); s2 += __shfl_xor(s2, 4);
        s1 += __shfl_xor(s1, 8); s2 += __shfl_xor(s2, 8);
        if (fm == 0) { sS1[wv][q * 4 + r] = s1; sS2[wv][q * 4 + r] = s2; }
    }
    __syncthreads();
#pragma unroll
    for (int r = 0; r < 4; ++r) {
        int row = q * 4 + r;
        int m = m0 + row;
        float S1 = sS1[0][row] + sS1[1][row] + sS1[2][row] + sS1[3][row];
        float S2 = sS2[0][row] + sS2[1][row] + sS2[2][row] + sS2[3][row];
        float mean = S1 * (1.f / DMODEL);
        float var  = S2 * (1.f / DMODEL) - mean * mean;
        float rstd = rsqrtf(var + 1e-5f);
#pragma unroll
        for (int j = 0; j < 3; ++j) {
            int col = (wv * 3 + j) * 16 + fm;
            float o = (v[j][r] - mean) * rstd * slw[col] + slb[col];
            if (outf) outf[(size_t)m * DMODEL + col] = o;
            else      hn[(size_t)m * DMODEL + col] = __float2bfloat16(o);
        }
    }
}

// ---------------- fused: in_proj GEMM + conv + SiLU + x_proj + dt ----------------
// 196 blocks x 8 tokens. MFMA tile: M=16 rows = tokens g0-3..g0+12 (rows 0..10
// live: 3 halo + 8 own), N=768, K=192. W streamed in K-slices of 32 through
// LDS. Epilogue: z-half -> zbuf (f32), xin-half -> LDS -> conv(l-masked taps)
// -> SiLU -> u + LDS -> x_proj -> dt/B/C. xin and xz never touch global.
struct FaEpi { float sxin[12 * 384]; float su[8 * 384]; float sx[8 * 48]; };
union FaU { short Ws[768 * LDA]; FaEpi e; };   // 61,440 B

__global__ __launch_bounds__(256) void in_conv_xproj(
    const __hip_bfloat16* __restrict__ hn, const short* __restrict__ wi,
    const float* __restrict__ cw, const float* __restrict__ cb,
    const float* __restrict__ xpwl, const float* __restrict__ dtwl,
    const float* __restrict__ dtb, float* __restrict__ zbuf,
    float* __restrict__ u, float* __restrict__ dtg, float* __restrict__ bcg)
{
    __shared__ short As[16 * ALD];
    __shared__ FaU sm;
    int tid = threadIdx.x;
    int g0 = blockIdx.x * 8;
    int wv = tid >> 6, lane = tid & 63;
    int fm = lane & 15, q = lane >> 4;

    // stage A once: rows 0..15 = tokens g0-3+row (rows >=11 and ar<0 zeroed)
    const short* Ab = (const short*)hn;
    for (int idx = tid; idx < 16 * 24; idx += 256) {
        int row = idx / 24, kc8 = (idx % 24) * 8;
        int ar = g0 - 3 + row;
        short8 v = {0,0,0,0,0,0,0,0};
        if (row < 11 && ar >= 0) v = *(const short8*)&Ab[(size_t)ar * DMODEL + kc8];
        *(short8*)&As[row * ALD + kc8] = v;
    }

    floatx4 acc[12];
#pragma unroll
    for (int j = 0; j < 12; ++j) acc[j] = (floatx4){0.f, 0.f, 0.f, 0.f};

    // K-loop: stream W[768][32] slices through LDS (first sync also covers As)
    for (int k0 = 0; k0 < DMODEL; k0 += 32) {
        for (int idx = tid; idx < 768 * 4; idx += 256) {
            int n = idx >> 2, kc = (idx & 3) * 8;
            *(short8*)&sm.Ws[n * LDA + kc] = *(const short8*)&wi[(size_t)n * DMODEL + k0 + kc];
        }
        __syncthreads();
        short8 af = *(const short8*)&As[fm * ALD + k0 + q * 8];
#pragma unroll
        for (int j = 0; j < 12; ++j) {
            short8 bf = *(const short8*)&sm.Ws[((wv * 12 + j) * 16 + fm) * LDA + q * 8];
            acc[j] = __builtin_amdgcn_mfma_f32_16x16x32_bf16(af, bf, acc[j], 0, 0, 0);
        }
        __syncthreads();
    }

    // scatter: xin-half (cols<384) -> LDS sxin rows 0..10; z-half -> zbuf
#pragma unroll
    for (int j = 0; j < 12; ++j) {
        int col = wv * 192 + j * 16 + fm;
#pragma unroll
        for (int r = 0; r < 4; ++r) {
            int row = q * 4 + r;
            float val = acc[j][r];
            if (col < 384) {
                if (row < 11) sm.e.sxin[row * 384 + col] = val;
            } else {
                int t = row - 3;
                if (t >= 0 && t < 8) zbuf[(size_t)(g0 + t) * 384 + (col - 384)] = val;
            }
        }
    }
    __syncthreads();

    // conv + SiLU (taps l-masked: handles sequence starts and batch seams)
    for (int idx = tid; idx < 8 * 384; idx += 256) {
        int t = idx / 384, d = idx % 384;
        int l = (g0 + t) % LSEQ;
        float4 w4 = *(const float4*)&cw[d * 4];
        float a = cb[d] + sm.e.sxin[(t + 3) * 384 + d] * w4.w;
        if (l >= 1) a += sm.e.sxin[(t + 2) * 384 + d] * w4.z;
        if (l >= 2) a += sm.e.sxin[(t + 1) * 384 + d] * w4.y;
        if (l >= 3) a += sm.e.sxin[(t    ) * 384 + d] * w4.x;
        float sig = 1.f / (1.f + __expf(-a));
        float val = a * sig;
        sm.e.su[idx] = val;
        u[(size_t)(g0 + t) * 384 + d] = val;
    }
    __syncthreads();

    // x_proj: wave wv -> tokens wv and wv+4; lane e<44 -> output e
    {
        int e_ = tid & 63;
        if (e_ < 44) {
#pragma unroll
            for (int half = 0; half < 2; ++half) {
                int t = wv + half * 4;
                const float* ur = &sm.e.su[t * 384];
                float a0 = 0.f, a1 = 0.f, a2 = 0.f, a3 = 0.f;
                for (int jj = 0; jj < 384; jj += 4) {
                    a0 += ur[jj]     * xpwl[(jj    ) * 44 + e_];
                    a1 += ur[jj + 1] * xpwl[(jj + 1) * 44 + e_];
                    a2 += ur[jj + 2] * xpwl[(jj + 2) * 44 + e_];
                    a3 += ur[jj + 3] * xpwl[(jj + 3) * 44 + e_];
                }
                sm.e.sx[t * 48 + e_] = (a0 + a1) + (a2 + a3);
            }
        }
    }
    __syncthreads();

    // dt = softplus(sx[:, :12] @ dtwT + dtb); B/C passthrough
    for (int idx = tid; idx < 8 * 384; idx += 256) {
        int t = idx / 384, d = idx % 384;
        float a = dtb[d];
#pragma unroll
        for (int r = 0; r < DTRANK; ++r) a += sm.e.sx[t * 48 + r] * dtwl[r * 384 + d];
        float sp = (a > 20.f) ? a : log1pf(__expf(a));
        dtg[(size_t)(g0 + t) * 384 + d] = sp;
    }
    {
        int t = tid >> 5, j = tid & 31;
        bcg[(size_t)(g0 + t) * 32 + j] = sm.e.sx[t * 48 + 12 + j];
    }
}

// ---------------- selective scan + gating (3-phase, R7; z from zbuf) ----------------
__global__ __launch_bounds__(256) void scan_kernel(
    const float* __restrict__ u, const float* __restrict__ dtg,
    const float* __restrict__ bc, const float* __restrict__ zbuf,
    const float* __restrict__ Alog, const float* __restrict__ Dp,
    __hip_bfloat16* __restrict__ y)
{
    __shared__ float sdt[TCH][16];
    __shared__ float su_[TCH][16];
    __shared__ float sz_[TCH][16];
    __shared__ float sB_[TCH][16];
    __shared__ float sC_[TCH][16];
    __shared__ float sprod[TCH][SPAD];

    int b  = blockIdx.x / 24;
    int dg = blockIdx.x % 24;
    int tid = threadIdx.x;
    int s = tid & 15, dl = tid >> 4;
    int d = dg * 16 + dl;
    float Ads = -expf(Alog[d * DSTATE + s]);
    float Dd2 = Dp[dg * 16 + (tid & 15)];
    float h = 0.f;

    for (int c0 = 0; c0 < LSEQ; c0 += TCH) {
        if (tid < TCH * 4) {
            int t = tid >> 2, j4 = (tid & 3) * 4;
            size_t tok = (size_t)(b * LSEQ + c0 + t);
            *(float4*)&sdt[t][j4] = *(const float4*)&dtg [tok * DINNER + dg * 16 + j4];
            *(float4*)&su_[t][j4] = *(const float4*)&u   [tok * DINNER + dg * 16 + j4];
            *(float4*)&sz_[t][j4] = *(const float4*)&zbuf[tok * DINNER + dg * 16 + j4];
            *(float4*)&sB_[t][j4] = *(const float4*)&bc  [tok * 32 + j4];
            *(float4*)&sC_[t][j4] = *(const float4*)&bc  [tok * 32 + 16 + j4];
        }
        __syncthreads();

#pragma unroll 7
        for (int t = 0; t < TCH; ++t) {
            float dtv = sdt[t][dl];
            float uv  = su_[t][dl];
            float Bv  = sB_[t][s];
            float Cv  = sC_[t][s];
            float dA  = __expf(dtv * Ads);
            h = dA * h + (dtv * uv) * Bv;
            sprod[t][dl * 17 + s] = h * Cv;
        }
        __syncthreads();

        for (int i = tid; i < TCH * 16; i += 256) {
            int t = i >> 4, dl2 = i & 15;
            float sum = 0.f;
#pragma unroll
            for (int j = 0; j < 16; ++j) sum += sprod[t][dl2 * 17 + j];
            float uv = su_[t][dl2];
            float zv = sz_[t][dl2];
            float sig = 1.f / (1.f + __expf(-zv));
            y[(size_t)(b * LSEQ + c0 + t) * DINNER + dg * 16 + dl2] =
                __float2bfloat16((sum + uv * Dd2) * (zv * sig));
        }
        __syncthreads();
    }
}

// ---------------------------------------------------------------------------
extern "C" void kernel_launch(void* const* d_in, const int* in_sizes, int n_in,
                              void* d_out, int out_size, void* d_ws, size_t ws_size,
                              hipStream_t stream)
{
    const float* x         = (const float*)d_in[0];
    const float* pe_w      = (const float*)d_in[1];
    const float* pe_b      = (const float*)d_in[2];
    const float* norm_w    = (const float*)d_in[3];
    const float* norm_b    = (const float*)d_in[4];
    const float* in_proj_w = (const float*)d_in[5];
    const float* conv_w    = (const float*)d_in[6];
    const float* conv_b    = (const float*)d_in[7];
    const float* xproj_w   = (const float*)d_in[8];
    const float* dtproj_w  = (const float*)d_in[9];
    const float* dtproj_b  = (const float*)d_in[10];
    const float* A_log     = (const float*)d_in[11];
    const float* D_param   = (const float*)d_in[12];
    const float* outproj_w = (const float*)d_in[13];
    const float* normf_w   = (const float*)d_in[14];
    const float* normf_b   = (const float*)d_in[15];

    float* ws = (float*)d_ws;
    float* residual = ws;                       // 301056 f32
    float* zbuf     = residual + 301056;        // 602112 f32 (z-half only)
    float* ubuf     = zbuf + 602112;            // 602112 f32
    float* dtbuf    = ubuf + 602112;            // 602112 f32
    float* bcbuf    = dtbuf + 602112;           // 50176 f32
    __hip_bfloat16* hn      = (__hip_bfloat16*)(ws + 2759680);  // 301056 bf16
    __hip_bfloat16* ybf     = (__hip_bfloat16*)(ws + 2910208);  // 602112 bf16
    __hip_bfloat16* patches = (__hip_bfloat16*)(ws + 3211264);  // 1204224 bf16
    short* w_in  = (short*)(ws + 3813376);      // 3538944 bf16
    short* w_out = (short*)(ws + 5582848);      // 1769472 bf16
    short* w_pe  = (short*)(ws + 6467584);      // 147456 bf16
    float* xpwT  = ws + 6541312;                // 405504 f32
    float* dtwT  = xpwT + 405504;               // 110592 f32

    prep<<<12048, 256, 0, stream>>>(
        in_proj_w, outproj_w, pe_w, xproj_w, dtproj_w, x,
        w_in, w_out, w_pe, xpwT, dtwT, patches);
    gemm_ln<768><<<98, 256, 0, stream>>>(
        patches, w_pe, pe_b, residual, hn, nullptr, norm_w, norm_b, 0);

    for (int i = 0; i < DEPTH; ++i) {
        int last = (i == DEPTH - 1);
        in_conv_xproj<<<196, 256, 0, stream>>>(
            hn, w_in + (size_t)i * 768 * DMODEL,
            conv_w + (size_t)i * DINNER * 4, conv_b + (size_t)i * DINNER,
            xpwT + (size_t)i * 384 * 44, dtwT + (size_t)i * 12 * 384,
            dtproj_b + (size_t)i * DINNER, zbuf, ubuf, dtbuf, bcbuf);
        scan_kernel<<<192, 256, 0, stream>>>(
            ubuf, dtbuf, bcbuf, zbuf, A_log + (size_t)i * DINNER * DSTATE,
            D_param + (size_t)i * DINNER, ybf);
        gemm_ln<384><<<98, 256, 0, stream>>>(
            ybf, w_out + (size_t)i * DMODEL * DINNER, nullptr, residual, hn,
            last ? (float*)d_out : nullptr,
            last ? normf_w : norm_w + (i + 1) * DMODEL,
            last ? normf_b : norm_b + (i + 1) * DMODEL,
            1);
    }
}

// Round 5
// 1730.776 us; speedup vs baseline: 2.1842x; 1.1068x over previous
//
#include <hip/hip_runtime.h>
#include <hip/hip_bf16.h>

// ---------------------------------------------------------------------------
// VisionMamba, round 16: R12 split pipeline (1421us verified) with ONE change:
// conv_xproj_dt's x_proj/dt loops read LDS-staged weight tables instead of
// chasing L2 latency. Everything else byte-identical to R12.
// B=8, L=196, D_MODEL=192, D_INNER=384, D_STATE=16, DT_RANK=12, DEPTH=24.
//
// Evidence trail: R13 (device barriers) 3780us; R14 (XCD-pinned) 2042us;
// R15 (fused front half) 1916us with in_conv_xproj=64us measured. Algebra
// R15 vs R12: gemm_in+conv_xproj_dt+gap ~= 43us/layer, scan+gemm_ln+2gaps
// ~= 14us/layer -> conv_xproj_dt ~30us is the whale. Its x_proj loop does
// 768 L2 loads/lane (xpwT) and dt does 144 (dtwT), latency-chained, 44/64
// lanes, 1.5 blocks/CU. Fix: xpwT double-buffered 32x44 f32 chunks in LDS
// (staging overlapped, 1 sync/chunk); dtwT staged whole (18.4KB). LDS 47.4KB
// -> 3 blocks/CU. f32 throughout -> numerics unchanged (reassociation only).
// ---------------------------------------------------------------------------

#define NTOK   1568   // B * L
#define DMODEL 192
#define DINNER 384
#define DSTATE 16
#define DTRANK 12
#define DEPTH  24
#define LSEQ   196
#define TCH    49     // scan time-chunk (196 = 4*49)
#define LDA    40     // LDS row stride in bf16 elements (80B)

typedef __attribute__((ext_vector_type(8))) short short8;
typedef __attribute__((ext_vector_type(4))) short short4v;
typedef __attribute__((ext_vector_type(4))) float floatx4;

__device__ inline short f2bf(float f) {
    __hip_bfloat16 h = __float2bfloat16(f);
    return *reinterpret_cast<short*>(&h);
}

// ---------------- merged pre-stage: weight cvt + transposes + im2col ----------------
#define PR1 884736
#define PR2 1327104   // +442368
#define PR3 1363968   // +36864
#define PR4 1769472   // +405504
#define PR5 1880064   // +110592
#define PR6 3084288   // +1204224
__global__ __launch_bounds__(256) void prep(
    const float* __restrict__ inw, const float* __restrict__ outw,
    const float* __restrict__ pew, const float* __restrict__ xpw,
    const float* __restrict__ dtw, const float* __restrict__ x,
    short* __restrict__ w_in, short* __restrict__ w_out,
    short* __restrict__ w_pe, float* __restrict__ xpwT,
    float* __restrict__ dtwT, __hip_bfloat16* __restrict__ patches)
{
    int idx = blockIdx.x * 256 + threadIdx.x;
    if (idx < PR3) {
        float4 v; short* dst;
        if (idx < PR1)      { v = ((const float4*)inw)[idx];        dst = w_in  + (size_t)idx * 4; }
        else if (idx < PR2) { int i = idx - PR1; v = ((const float4*)outw)[i]; dst = w_out + (size_t)i * 4; }
        else                { int i = idx - PR2; v = ((const float4*)pew)[i];  dst = w_pe  + (size_t)i * 4; }
        short4v o;
        o[0] = f2bf(v.x); o[1] = f2bf(v.y); o[2] = f2bf(v.z); o[3] = f2bf(v.w);
        *(short4v*)dst = o;
    } else if (idx < PR4) {
        int i = idx - PR3;                    // xpwT[layer][k][e] = xpw[layer][e][k]
        int layer = i / 16896, rem = i % 16896;
        int k = rem / 44, e = rem % 44;
        xpwT[i] = xpw[(size_t)layer * 16896 + e * 384 + k];
    } else if (idx < PR5) {
        int i = idx - PR4;                    // dtwT[layer][r][d] = dtw[layer][d][r]
        int layer = i / 4608, rem = i % 4608;
        int r = rem / 384, d = rem % 384;
        dtwT[i] = dtw[(size_t)layer * 4608 + d * 12 + r];
    } else if (idx < PR6) {
        int i = idx - PR5;                    // im2col
        int tok = i / 768, e = i % 768;
        int b = tok / LSEQ, l = tok % LSEQ;
        int py = l / 14, px = l % 14;
        int ic = e >> 8, rem = e & 255, ky = rem >> 4, kx = rem & 15;
        patches[i] = __float2bfloat16(x[((b * 3 + ic) * 224 + py * 16 + ky) * 224 + px * 16 + kx]);
    }
}

// ---------------- gemm_in: xz[M,768] = hn[M,192] @ W[768,192]^T ----------------
template<int K>
__global__ __launch_bounds__(256) void gemm_in(
    const __hip_bfloat16* __restrict__ A, const short* __restrict__ Wb,
    float* __restrict__ C, int M, int N)
{
    __shared__ short As[64 * LDA];
    __shared__ short Ws[64 * LDA];
    int tid = threadIdx.x;
    int m0 = blockIdx.x * 64, n0 = blockIdx.y * 64;
    int wv = tid >> 6, lane = tid & 63;
    int fm = lane & 15, q = lane >> 4;
    int row = tid >> 2, kc = (tid & 3) * 8;
    const short* Ab = (const short*)A;
    floatx4 acc[4];
#pragma unroll
    for (int nt = 0; nt < 4; ++nt) acc[nt] = (floatx4){0.f, 0.f, 0.f, 0.f};

#pragma unroll
    for (int k0 = 0; k0 < K; k0 += 32) {
        {
            int m = m0 + row;
            short8 v = {0,0,0,0,0,0,0,0};
            if (m < M) v = *(const short8*)&Ab[(size_t)m * K + k0 + kc];
            *(short8*)&As[row * LDA + kc] = v;
        }
        {
            short8 w = *(const short8*)&Wb[(size_t)(n0 + row) * K + k0 + kc];
            *(short8*)&Ws[row * LDA + kc] = w;
        }
        __syncthreads();
        short8 af = *(const short8*)&As[(wv * 16 + fm) * LDA + q * 8];
#pragma unroll
        for (int nt = 0; nt < 4; ++nt) {
            short8 bf = *(const short8*)&Ws[(nt * 16 + fm) * LDA + q * 8];
            acc[nt] = __builtin_amdgcn_mfma_f32_16x16x32_bf16(af, bf, acc[nt], 0, 0, 0);
        }
        __syncthreads();
    }
#pragma unroll
    for (int nt = 0; nt < 4; ++nt) {
        int col = n0 + nt * 16 + fm;
#pragma unroll
        for (int r = 0; r < 4; ++r) {
            int mrow = m0 + wv * 16 + q * 4 + r;
            if (mrow < M) C[(size_t)mrow * N + col] = acc[nt][r];
        }
    }
}

// ---------------- gemm_ln: 16-row tiles, pipelined LDS, fused residual+LN ----------------
template<int K>
__global__ __launch_bounds__(256) void gemm_ln(
    const __hip_bfloat16* __restrict__ A, const short* __restrict__ Wb,
    const float* __restrict__ bias, float* __restrict__ residual,
    __hip_bfloat16* __restrict__ hn, float* __restrict__ outf,
    const float* __restrict__ lnw, const float* __restrict__ lnb,
    int accumulate)
{
    __shared__ short As[16 * LDA];
    __shared__ short Ws[192 * LDA];
    __shared__ float slw[192], slb[192], sbias[192];
    __shared__ float sS1[4][16], sS2[4][16];
    int tid = threadIdx.x;
    int m0 = blockIdx.x * 16;
    int wv = tid >> 6, lane = tid & 63;
    int fm = lane & 15, q = lane >> 4;
    int wrow = tid >> 2, kc = (tid & 3) * 8;
    if (tid < 192) {
        slw[tid] = lnw[tid];
        slb[tid] = lnb[tid];
        sbias[tid] = bias ? bias[tid] : 0.f;
    }
    const short* Ab = (const short*)A;
    floatx4 acc[3];
#pragma unroll
    for (int j = 0; j < 3; ++j) acc[j] = (floatx4){0.f, 0.f, 0.f, 0.f};

    short8 aR = {0,0,0,0,0,0,0,0};
    short8 wR[3];
    if (tid < 64) aR = *(const short8*)&Ab[(size_t)(m0 + (tid >> 2)) * K + kc];
#pragma unroll
    for (int j = 0; j < 3; ++j)
        wR[j] = *(const short8*)&Wb[(size_t)(wrow + 64 * j) * K + kc];

    for (int k0 = 0; k0 < K; k0 += 32) {
        if (tid < 64) *(short8*)&As[(tid >> 2) * LDA + kc] = aR;
#pragma unroll
        for (int j = 0; j < 3; ++j)
            *(short8*)&Ws[(wrow + 64 * j) * LDA + kc] = wR[j];
        __syncthreads();
        int kn = k0 + 32;
        if (kn < K) {
            if (tid < 64) aR = *(const short8*)&Ab[(size_t)(m0 + (tid >> 2)) * K + kn + kc];
#pragma unroll
            for (int j = 0; j < 3; ++j)
                wR[j] = *(const short8*)&Wb[(size_t)(wrow + 64 * j) * K + kn + kc];
        }
        short8 af = *(const short8*)&As[fm * LDA + q * 8];
#pragma unroll
        for (int j = 0; j < 3; ++j) {
            int ct = wv * 3 + j;
            short8 bf = *(const short8*)&Ws[(ct * 16 + fm) * LDA + q * 8];
            acc[j] = __builtin_amdgcn_mfma_f32_16x16x32_bf16(af, bf, acc[j], 0, 0, 0);
        }
        __syncthreads();
    }

    float v[3][4];
#pragma unroll
    for (int r = 0; r < 4; ++r) {
        int m = m0 + q * 4 + r;
#pragma unroll
        for (int j = 0; j < 3; ++j) {
            int col = (wv * 3 + j) * 16 + fm;
            float t = acc[j][r] + sbias[col];
            if (accumulate) t += residual[(size_t)m * DMODEL + col];
            v[j][r] = t;
        }
    }
#pragma unroll
    for (int r = 0; r < 4; ++r) {
        int m = m0 + q * 4 + r;
#pragma unroll
        for (int j = 0; j < 3; ++j)
            residual[(size_t)m * DMODEL + (wv * 3 + j) * 16 + fm] = v[j][r];
    }
#pragma unroll
    for (int r = 0; r < 4; ++r) {
        float s1 = v[0][r] + v[1][r] + v[2][r];
        float s2 = v[0][r]*v[0][r] + v[1][r]*v[1][r] + v[2][r]*v[2][r];
        s1 += __shfl_xor(s1, 1); s2 += __shfl_xor(s2, 1);
        s1 += __shfl_xor(s1, 2); s2 += __shfl_xor(s2, 2);
        s1 += __shfl_xor(s1, 4); s2 += __shfl_xor(s2, 4);
        s1 += __shfl_xor(s1, 8); s2 += __shfl_xor(s2, 8);
        if (fm == 0) { sS1[wv][q * 4 + r] = s1; sS2[wv][q * 4 + r] = s2; }
    }
    __syncthreads();
#pragma unroll
    for (int r = 0; r < 4; ++r) {
        int row = q * 4 + r;
        int m = m0 + row;
        float S1 = sS1[0][row] + sS1[1][row] + sS1[2][row] + sS1[3][row];
        float S2 = sS2[0][row] + sS2[1][row] + sS2[2][row] + sS2[3][row];
        float mean = S1 * (1.f / DMODEL);
        float var  = S2 * (1.f / DMODEL) - mean * mean;
        float rstd = rsqrtf(var + 1e-5f);
#pragma unroll
        for (int j = 0; j < 3; ++j) {
            int col = (wv * 3 + j) * 16 + fm;
            float o = (v[j][r] - mean) * rstd * slw[col] + slb[col];
            if (outf) outf[(size_t)m * DMODEL + col] = o;
            else      hn[(size_t)m * DMODEL + col] = __float2bfloat16(o);
        }
    }
}

// ---------------- conv + silu + x_proj + dt : 4 tokens/block, LDS-staged tables ------
// R16: x_proj reads xpwT via double-buffered 32x44 f32 LDS chunks (staging
// overlapped with compute, 1 sync/chunk); dt reads dtwT from a full 18.4KB
// LDS stage. Kills the 768+144 per-lane L2 latency chains of R12.
__global__ __launch_bounds__(256) void conv_xproj_dt(
    const float* __restrict__ xz, const float* __restrict__ cw,
    const float* __restrict__ cb, const float* __restrict__ xpwT,
    const float* __restrict__ dtwT, const float* __restrict__ dtb,
    float* __restrict__ u, float* __restrict__ dtg, float* __restrict__ bcg)
{
    __shared__ float sxz[7 * 384];
    __shared__ float su[4 * 384];
    __shared__ float sx[4 * 48];
    __shared__ float sxp[2][32 * 44];
    __shared__ float sdtw[12 * 384];
    int blk = blockIdx.x;
    int b = blk / 49, c = blk % 49;
    int l0 = c * 4;
    int tid = threadIdx.x;

    // stage dtwT whole (4608 f32, coalesced) + xin halo tile + first xproj chunk
    for (int i = tid; i < 12 * 384; i += 256) sdtw[i] = dtwT[i];
    for (int idx = tid; idx < 7 * 384; idx += 256) {
        int t = idx / 384, d = idx % 384;
        int l = l0 - 3 + t;
        sxz[idx] = (l >= 0) ? xz[(size_t)(b * LSEQ + l) * 768 + d] : 0.f;
    }
    for (int i = tid; i < 32 * 44; i += 256) sxp[0][i] = xpwT[i];
    __syncthreads();

    // conv + SiLU, 4 tokens x 384 channels
    for (int idx = tid; idx < 4 * 384; idx += 256) {
        int t = idx / 384, d = idx % 384;
        float4 w4 = *(const float4*)&cw[d * 4];
        float acc = cb[d]
            + sxz[t * 384 + d]       * w4.x
            + sxz[(t + 1) * 384 + d] * w4.y
            + sxz[(t + 2) * 384 + d] * w4.z
            + sxz[(t + 3) * 384 + d] * w4.w;
        float sig = 1.f / (1.f + __expf(-acc));
        float val = acc * sig;
        su[idx] = val;
        u[(size_t)(b * LSEQ + l0 + t) * 384 + d] = val;
    }
    __syncthreads();

    // x_proj: wave wv -> token wv; lane e<44 -> output e. K chunked by 32,
    // double-buffered LDS weights; su reads are wave-broadcast.
    {
        int wv = tid >> 6, e = tid & 63;
        float a0 = 0.f, a1 = 0.f, a2 = 0.f, a3 = 0.f;
        for (int ch = 0; ch < 12; ++ch) {
            if (ch + 1 < 12) {
                for (int i = tid; i < 32 * 44; i += 256)
                    sxp[(ch + 1) & 1][i] = xpwT[(ch + 1) * (32 * 44) + i];
            }
            if (e < 44) {
                const float* ur = &su[wv * 384 + ch * 32];
                const float* wp = &sxp[ch & 1][0];
#pragma unroll
                for (int j = 0; j < 32; j += 4) {
                    a0 += ur[j]     * wp[(j    ) * 44 + e];
                    a1 += ur[j + 1] * wp[(j + 1) * 44 + e];
                    a2 += ur[j + 2] * wp[(j + 2) * 44 + e];
                    a3 += ur[j + 3] * wp[(j + 3) * 44 + e];
                }
            }
            __syncthreads();
        }
        if (e < 44) sx[wv * 48 + e] = (a0 + a1) + (a2 + a3);
    }
    __syncthreads();

    // dt = softplus(sx[:, :12] @ dtwT + dtb), dtwT from LDS
    for (int idx = tid; idx < 4 * 384; idx += 256) {
        int t = idx / 384, d = idx % 384;
        float acc = dtb[d];
#pragma unroll
        for (int r = 0; r < DTRANK; ++r) acc += sx[t * 48 + r] * sdtw[r * 384 + d];
        float sp = (acc > 20.f) ? acc : log1pf(__expf(acc));
        dtg[(size_t)(b * LSEQ + l0 + t) * 384 + d] = sp;
    }
    // B/C per token
    if (tid < 128) {
        int t = tid >> 5, j = tid & 31;
        bcg[(size_t)(b * LSEQ + l0 + t) * 32 + j] = sx[t * 48 + 12 + j];
    }
}

// ---------------- selective scan + gating (3-phase, R7) ----------------
#define SPAD 272
__global__ __launch_bounds__(256) void scan_kernel(
    const float* __restrict__ u, const float* __restrict__ dtg,
    const float* __restrict__ bc, const float* __restrict__ xz,
    const float* __restrict__ Alog, const float* __restrict__ Dp,
    __hip_bfloat16* __restrict__ y)
{
    __shared__ float sdt[TCH][16];
    __shared__ float su_[TCH][16];
    __shared__ float sz_[TCH][16];
    __shared__ float sB_[TCH][16];
    __shared__ float sC_[TCH][16];
    __shared__ float sprod[TCH][SPAD];

    int b  = blockIdx.x / 24;
    int dg = blockIdx.x % 24;
    int tid = threadIdx.x;
    int s = tid & 15, dl = tid >> 4;
    int d = dg * 16 + dl;
    float Ads = -expf(Alog[d * DSTATE + s]);
    float Dd2 = Dp[dg * 16 + (tid & 15)];
    float h = 0.f;

    for (int c0 = 0; c0 < LSEQ; c0 += TCH) {
        if (tid < TCH * 4) {
            int t = tid >> 2, j4 = (tid & 3) * 4;
            size_t tok = (size_t)(b * LSEQ + c0 + t);
            *(float4*)&sdt[t][j4] = *(const float4*)&dtg[tok * DINNER + dg * 16 + j4];
            *(float4*)&su_[t][j4] = *(const float4*)&u  [tok * DINNER + dg * 16 + j4];
            *(float4*)&sz_[t][j4] = *(const float4*)&xz [tok * 768 + DINNER + dg * 16 + j4];
            *(float4*)&sB_[t][j4] = *(const float4*)&bc [tok * 32 + j4];
            *(float4*)&sC_[t][j4] = *(const float4*)&bc [tok * 32 + 16 + j4];
        }
        __syncthreads();

#pragma unroll 7
        for (int t = 0; t < TCH; ++t) {
            float dtv = sdt[t][dl];
            float uv  = su_[t][dl];
            float Bv  = sB_[t][s];
            float Cv  = sC_[t][s];
            float dA  = __expf(dtv * Ads);
            h = dA * h + (dtv * uv) * Bv;
            sprod[t][dl * 17 + s] = h * Cv;
        }
        __syncthreads();

        for (int i = tid; i < TCH * 16; i += 256) {
            int t = i >> 4, dl2 = i & 15;
            float sum = 0.f;
#pragma unroll
            for (int j = 0; j < 16; ++j) sum += sprod[t][dl2 * 17 + j];
            float uv = su_[t][dl2];
            float zv = sz_[t][dl2];
            float sig = 1.f / (1.f + __expf(-zv));
            y[(size_t)(b * LSEQ + c0 + t) * DINNER + dg * 16 + dl2] =
                __float2bfloat16((sum + uv * Dd2) * (zv * sig));
        }
        __syncthreads();
    }
}

// ---------------------------------------------------------------------------
extern "C" void kernel_launch(void* const* d_in, const int* in_sizes, int n_in,
                              void* d_out, int out_size, void* d_ws, size_t ws_size,
                              hipStream_t stream)
{
    const float* x         = (const float*)d_in[0];
    const float* pe_w      = (const float*)d_in[1];
    const float* pe_b      = (const float*)d_in[2];
    const float* norm_w    = (const float*)d_in[3];
    const float* norm_b    = (const float*)d_in[4];
    const float* in_proj_w = (const float*)d_in[5];
    const float* conv_w    = (const float*)d_in[6];
    const float* conv_b    = (const float*)d_in[7];
    const float* xproj_w   = (const float*)d_in[8];
    const float* dtproj_w  = (const float*)d_in[9];
    const float* dtproj_b  = (const float*)d_in[10];
    const float* A_log     = (const float*)d_in[11];
    const float* D_param   = (const float*)d_in[12];
    const float* outproj_w = (const float*)d_in[13];
    const float* normf_w   = (const float*)d_in[14];
    const float* normf_b   = (const float*)d_in[15];

    float* ws = (float*)d_ws;
    float* residual = ws;                       // 301056 f32
    float* xz       = residual + 301056;        // 1204224 f32
    float* ubuf     = xz + 1204224;             // 602112 f32
    float* dtbuf    = ubuf + 602112;            // 602112 f32
    float* bcbuf    = dtbuf + 602112;           // 50176 f32
    __hip_bfloat16* hn      = (__hip_bfloat16*)(ws + 2759680);  // 301056 bf16
    __hip_bfloat16* ybf     = (__hip_bfloat16*)(ws + 2910208);  // 602112 bf16
    __hip_bfloat16* patches = (__hip_bfloat16*)(ws + 3211264);  // 1204224 bf16
    short* w_in  = (short*)(ws + 3813376);      // 3538944 bf16
    short* w_out = (short*)(ws + 5582848);      // 1769472 bf16
    short* w_pe  = (short*)(ws + 6467584);      // 147456 bf16
    float* xpwT  = ws + 6541312;                // 405504 f32
    float* dtwT  = xpwT + 405504;               // 110592 f32

    prep<<<12048, 256, 0, stream>>>(
        in_proj_w, outproj_w, pe_w, xproj_w, dtproj_w, x,
        w_in, w_out, w_pe, xpwT, dtwT, patches);
    gemm_ln<768><<<98, 256, 0, stream>>>(
        patches, w_pe, pe_b, residual, hn, nullptr, norm_w, norm_b, 0);

    for (int i = 0; i < DEPTH; ++i) {
        int last = (i == DEPTH - 1);
        gemm_in<192><<<dim3(25, 12), 256, 0, stream>>>(
            hn, w_in + (size_t)i * 768 * DMODEL, xz, NTOK, 768);
        conv_xproj_dt<<<392, 256, 0, stream>>>(
            xz, conv_w + (size_t)i * DINNER * 4, conv_b + (size_t)i * DINNER,
            xpwT + (size_t)i * 384 * 44, dtwT + (size_t)i * 12 * 384,
            dtproj_b + (size_t)i * DINNER, ubuf, dtbuf, bcbuf);
        scan_kernel<<<192, 256, 0, stream>>>(
            ubuf, dtbuf, bcbuf, xz, A_log + (size_t)i * DINNER * DSTATE,
            D_param + (size_t)i * DINNER, ybf);
        gemm_ln<384><<<98, 256, 0, stream>>>(
            ybf, w_out + (size_t)i * DMODEL * DINNER, nullptr, residual, hn,
            last ? (float*)d_out : nullptr,
            last ? normf_w : norm_w + (i + 1) * DMODEL,
            last ? normf_b : norm_b + (i + 1) * DMODEL,
            1);
    }
}